// Round 1
// baseline (445.800 us; speedup 1.0000x reference)
//
#include <hip/hip_runtime.h>
#include <hip/hip_bf16.h>
#include <stdint.h>

#define D_MODEL 1024
#define NUM_HEADS 16
#define DK 64
#define BATCH 4
#define SEQ 2048
#define MTOT (BATCH * SEQ)   // 8192 tokens

typedef unsigned short u16;
typedef unsigned int u32;
typedef __bf16 bf16x8 __attribute__((ext_vector_type(8)));
typedef float f32x4 __attribute__((ext_vector_type(4)));
typedef short s16x4 __attribute__((ext_vector_type(4)));
typedef int   i32x4 __attribute__((ext_vector_type(4)));
typedef int   i32x2 __attribute__((ext_vector_type(2)));
typedef uint  u32x2 __attribute__((ext_vector_type(2)));

// v_mfma_f32_16x16x16_bf16 (gfx90a+ "_1k" builtin name): A,B = 2 VGPRs (4 bf16), C/D = 4.
__device__ __forceinline__ f32x4 mfma16(s16x4 a, s16x4 b, f32x4 c) {
  return __builtin_amdgcn_mfma_f32_16x16x16bf16_1k(a, b, c, 0, 0, 0);
}

__device__ __forceinline__ u16 f2bf(float f) {
  union { float f; unsigned u; } c; c.f = f;
  unsigned u = c.u + 0x7fffu + ((c.u >> 16) & 1u);   // RNE
  return (u16)(u >> 16);
}
// pack two f32 into bf16x2 (truncate) — 1 instr
__device__ __forceinline__ u32 pack_bf2(float f0, float f1) {
  return __builtin_amdgcn_perm(__float_as_uint(f1), __float_as_uint(f0), 0x07060302u);
}
__device__ __forceinline__ s16x4 cast_s16x4(u32 lo, u32 hi) {
  u32x2 t = {lo, hi};
  return (s16x4)t;
}

// async global->LDS, 16B per lane (GEMM staging; LDS dst contiguous per wave).
__device__ __forceinline__ void async16(void* g, void* lds) {
  __builtin_amdgcn_global_load_lds(
      (__attribute__((address_space(1))) void*)g,
      (__attribute__((address_space(3))) void*)lds,
      16, 0, 0);
}

// ---------------- f32 -> bf16, all 7 tensors in one dispatch ----------------
struct CvtArgs {
  const float* s[7];
  u16* d[7];
  int n[7];
};
__global__ __launch_bounds__(256)
void cvt_multi(CvtArgs a) {
  const int which = blockIdx.y;
  const int n = a.n[which];
  const int i = (blockIdx.x * 256 + threadIdx.x) * 8;
  if (i >= n) return;
  const float* s = a.s[which];
  u16* d = a.d[which];
  const float4 x = *(const float4*)(s + i);
  const float4 y = *(const float4*)(s + i + 4);
  *(ushort4*)(d + i)     = make_ushort4(f2bf(x.x), f2bf(x.y), f2bf(x.z), f2bf(x.w));
  *(ushort4*)(d + i + 4) = make_ushort4(f2bf(y.x), f2bf(y.y), f2bf(y.z), f2bf(y.w));
}

// ---------------- GEMM: C = A @ W^T + bias (m97 structure) ------------------
// A:[M,1024] bf16, W:[1024,1024] bf16 ([n][k]), bias f32.
// VT_OUT: C -> VtX[b*1024 + chan][SEQ] bf16, key dim chunk-interleaved:
//         within each 32-key chunk, key kt*16+qd*4+j stored at pos qd*8+kt*4+j
//         (so one dwordx4 in attn yields both 16x16x16 A-frags).
// F32_OUT: C f32 [M,1024].
template <bool VT_OUT, bool F32_OUT>
__global__ __launch_bounds__(256, 2)
void gemm_bt_bias(const u16* __restrict__ A, const u16* __restrict__ W,
                  const float* __restrict__ bias, void* __restrict__ Cv)
{
  __shared__ u16 As[128 * 32];
  __shared__ u16 Bs[128 * 32];
  const int t = threadIdx.x;
  const int w = t >> 6, l = t & 63;
  const int quad = l >> 4, lane16 = l & 15;
  const int m0 = blockIdx.x * 128;
  const int n0 = blockIdx.y * 128;
  const int wm = (w >> 1) * 64, wn = (w & 1) * 64;

  const int srow = t >> 2;
  const int scol = (t & 3) * 8;
  const u16* Ag = A + (long)(m0 + srow) * D_MODEL + scol;
  const u16* Wg = W + (long)(n0 + srow) * D_MODEL + scol;
  u16* As_w = As + w * 512;
  u16* Bs_w = Bs + w * 512;

  f32x4 acc[4][4] = {};

  for (int k0 = 0; k0 < D_MODEL; k0 += 32) {
    __syncthreads();
    async16((void*)(Ag + k0), As_w);
    async16((void*)(Ag + 64 * D_MODEL + k0), As_w + 2048);
    async16((void*)(Wg + k0), Bs_w);
    async16((void*)(Wg + 64 * D_MODEL + k0), Bs_w + 2048);
    __syncthreads();

    bf16x8 af[4], bfr[4];
#pragma unroll
    for (int i = 0; i < 4; ++i)
      af[i] = *(const bf16x8*)&As[(wm + i * 16 + lane16) * 32 + quad * 8];
#pragma unroll
    for (int i = 0; i < 4; ++i)
      bfr[i] = *(const bf16x8*)&Bs[(wn + i * 16 + lane16) * 32 + quad * 8];
#pragma unroll
    for (int i = 0; i < 4; ++i)
#pragma unroll
      for (int jn = 0; jn < 4; ++jn)
        acc[i][jn] = __builtin_amdgcn_mfma_f32_16x16x32_bf16(af[i], bfr[jn], acc[i][jn], 0, 0, 0);
  }

  if constexpr (VT_OUT) {
    // restage through LDS: T[dk_local(0..127)][key_local(0..127)], pad to 132
    __shared__ u16 T[128 * 132];
#pragma unroll
    for (int jn = 0; jn < 4; ++jn) {
      const int col = wn + jn * 16 + lane16;          // dk_local
      const float bb = bias[n0 + col];
#pragma unroll
      for (int i = 0; i < 4; ++i) {
        const int rbase = wm + i * 16 + quad * 4;     // key_local
#pragma unroll
        for (int r = 0; r < 4; ++r)
          T[col * 132 + rbase + r] = f2bf(acc[i][jn][r] + bb);
      }
    }
    __syncthreads();
    // coalesced, chunk-interleaved writeout: out pos 4a..4a+3 <- keys
    // (a>>3)*32 + ((a&7)>>1)*4 + (a&1)*16 + {0..3}
    const int bq = m0 >> 11, sbase = m0 & 2047;
    const int a = t & 31;
    const int keystart = ((a >> 3) * 32) + (((a & 7) >> 1) * 4) + ((a & 1) * 16);
    u16* orow = (u16*)Cv + ((long)bq * 1024 + n0) * SEQ + sbase + 4 * a;
#pragma unroll
    for (int pass = 0; pass < 16; ++pass) {
      const int dkl = (t >> 5) + 8 * pass;
      *(u32x2*)(orow + (long)dkl * SEQ) = *(const u32x2*)&T[dkl * 132 + keystart];
    }
  } else {
#pragma unroll
    for (int jn = 0; jn < 4; ++jn) {
      const int col = n0 + wn + jn * 16 + lane16;
      const float bb = bias[col];
#pragma unroll
      for (int i = 0; i < 4; ++i) {
        const int rbase = m0 + wm + i * 16 + quad * 4;
#pragma unroll
        for (int r = 0; r < 4; ++r) {
          const float v = acc[i][jn][r] + bb;
          if (F32_OUT) ((float*)Cv)[(long)(rbase + r) * D_MODEL + col] = v;
          else         ((u16*)Cv)[(long)(rbase + r) * D_MODEL + col] = f2bf(v);
        }
      }
    }
  }
}

// ---------------- Causal flash attention: split-K across the block ----------
// Block = 256 thr = 4 waves, owns ONE 32-row q-strip s. Wave w handles key
// chunks c = w, w+4, ... <= s (uniform ~ (s+1)/4 iterations per wave).
// Per-wave partial O^T / lsum merged via LDS (pure sums — no running max, so
// the merge is just an add). K-frags double-buffered in registers (prefetch
// c+4 during compute of c); V-frag loads issued before the QK MFMAs so their
// latency hides under QK+exp.
// Grid: 4096 linear blocks. Swizzle: all 64 blocks of one (b,h) map to the
// same XCD (id%8 round-robin assumption, perf-only); within a (b,h), heavy
// strips (large s) launch first.
// Q,K: [B,S,D] bf16. VtX: chunk-interleaved [b*1024+chan][SEQ]. O: [B,S,D] bf16.
__global__ __launch_bounds__(256, 4)
void attn_causal(const u16* __restrict__ Q, const u16* __restrict__ K,
                 const u16* __restrict__ VtX, u16* __restrict__ O)
{
  __shared__ float mrg[4][64][36];   // [wave][lane][oacc 0..31 | lsum 32,33] (36 = 16B-aligned stride)
  const int t = threadIdx.x;
  const int w = t >> 6, l = t & 63;
  const int quad = l >> 4, lane16 = l & 15;

  const int lin = blockIdx.x;        // 0..4095
  const int xcd = lin & 7;
  const int j = lin >> 3;
  const int bh = xcd * 8 + (j & 7);  // same bh -> same XCD (id%8 round-robin)
  const int s = 63 - (j >> 3);       // heavy strips first within each bh
  const int b = bh >> 4, h = bh & 15;
  const int qbase = s * 32;

  const long qkbase = (long)b * SEQ * D_MODEL + h * DK;

  // Q B-frags (x32): lane(q=lane16, quad) holds Q[q][ks*32+quad*8 ..+7]
  bf16x8 qf[2][2];
#pragma unroll
  for (int qi = 0; qi < 2; ++qi)
#pragma unroll
    for (int ks = 0; ks < 2; ++ks)
      qf[qi][ks] = *(const bf16x8*)&Q[qkbase +
          (long)(qbase + qi * 16 + lane16) * D_MODEL + ks * 32 + quad * 8];

  const u16* Kp = K + qkbase + (long)lane16 * D_MODEL + quad * 8;
  const u16* Vp = VtX + ((long)b * 1024 + h * 64 + lane16) * SEQ + quad * 8;

  f32x4 oacc[4][2] = {};     // [d][qi], O^T tiles (partial over this wave's chunks)
  float lsum[2] = {0.f, 0.f};
  const float SC = 0.125f * 1.4426950408889634f;

  auto loadK = [&](int c, bf16x8 (&kf)[2][2]) {
#pragma unroll
    for (int kt = 0; kt < 2; ++kt)
#pragma unroll
      for (int ks = 0; ks < 2; ++ks)
        kf[kt][ks] = *(const bf16x8*)(Kp + (long)(c * 32 + kt * 16) * D_MODEL + ks * 32);
  };

  auto compute = [&](int c, const bf16x8 (&kf)[2][2], bool diag) {
    // Vt A-frags: issue before QK so the load latency hides under QK+exp
    i32x4 vfd[4];
#pragma unroll
    for (int d = 0; d < 4; ++d)
      vfd[d] = *(const i32x4*)(Vp + (long)(d * 16) * SEQ + c * 32);

    // S^T = K·Q^T
    f32x4 st[2][2] = {};     // [kt][qi]
#pragma unroll
    for (int kt = 0; kt < 2; ++kt)
#pragma unroll
      for (int qi = 0; qi < 2; ++qi)
#pragma unroll
        for (int ks = 0; ks < 2; ++ks)
          st[kt][qi] = __builtin_amdgcn_mfma_f32_16x16x32_bf16(kf[kt][ks], qf[qi][ks], st[kt][qi], 0, 0, 0);

    // exp (base-2, folded scale), causal mask on diagonal chunk, pack
    u32 pb[2][2][2];         // [kt][qi][pair]
#pragma unroll
    for (int kt = 0; kt < 2; ++kt)
#pragma unroll
      for (int qi = 0; qi < 2; ++qi) {
        float pv[4];
#pragma unroll
        for (int r = 0; r < 4; ++r) {
          float p = exp2f(st[kt][qi][r] * SC);
          if (diag && (kt * 16 + quad * 4 + r > qi * 16 + lane16)) p = 0.f;
          pv[r] = p;
        }
        lsum[qi] += (pv[0] + pv[1]) + (pv[2] + pv[3]);
        pb[kt][qi][0] = pack_bf2(pv[0], pv[1]);
        pb[kt][qi][1] = pack_bf2(pv[2], pv[3]);
      }

    // O^T += Vt·P^T  (x16; P^T B-frag = packed scores, layout identity)
#pragma unroll
    for (int d = 0; d < 4; ++d) {
      const s16x4 va0 = cast_s16x4((u32)vfd[d].x, (u32)vfd[d].y);
      const s16x4 va1 = cast_s16x4((u32)vfd[d].z, (u32)vfd[d].w);
#pragma unroll
      for (int qi = 0; qi < 2; ++qi) {
        const s16x4 pb0 = cast_s16x4(pb[0][qi][0], pb[0][qi][1]);
        const s16x4 pb1 = cast_s16x4(pb[1][qi][0], pb[1][qi][1]);
        oacc[d][qi] = mfma16(va0, pb0, oacc[d][qi]);
        oacc[d][qi] = mfma16(va1, pb1, oacc[d][qi]);
      }
    }
  };

  // chunk loop, K-frags ping-pong double-buffered (static reg indexing only)
  int c = w;
  if (c <= s) {
    bf16x8 kfA[2][2], kfB[2][2];
    loadK(c, kfA);
    while (c + 8 <= s) {
      loadK(c + 4, kfB);
      compute(c, kfA, false);          // c <= s-8 < s: never diagonal
      loadK(c + 8, kfA);
      compute(c + 4, kfB, false);      // c+4 <= s-4 < s: never diagonal
      c += 8;
    }
    if (c + 4 <= s) {
      loadK(c + 4, kfB);
      compute(c, kfA, false);
      compute(c + 4, kfB, (c + 4) == s);
    } else {
      compute(c, kfA, c == s);
    }
  }

  // ---- merge the 4 waves' partials via LDS (pure sum: no max tracking) ----
  float* mw = &mrg[w][l][0];
#pragma unroll
  for (int d = 0; d < 4; ++d)
#pragma unroll
    for (int qi = 0; qi < 2; ++qi)
      *(f32x4*)&mw[d * 8 + qi * 4] = oacc[d][qi];
  mw[32] = lsum[0];
  mw[33] = lsum[1];
  __syncthreads();

  // wave w owns output d-tile d=w: sum the 4 partials
  f32x4 od[2] = {};
  float ls0 = 0.f, ls1 = 0.f;
#pragma unroll
  for (int ww = 0; ww < 4; ++ww) {
    const float* mr = &mrg[ww][l][0];
    od[0] += *(const f32x4*)&mr[w * 8 + 0];
    od[1] += *(const f32x4*)&mr[w * 8 + 4];
    ls0 += mr[32];
    ls1 += mr[33];
  }
  float linv[2];
  {
    float v0 = ls0;
    v0 += __shfl_xor(v0, 16); v0 += __shfl_xor(v0, 32);
    linv[0] = 1.f / v0;
    float v1 = ls1;
    v1 += __shfl_xor(v1, 16); v1 += __shfl_xor(v1, 32);
    linv[1] = 1.f / v1;
  }

  // epilogue: O[q][dk] = od^T / l ; lane writes 4 consecutive dk as b64
#pragma unroll
  for (int qi = 0; qi < 2; ++qi) {
    const long row = (long)b * SEQ + qbase + qi * 16 + lane16;
    const u32 p0 = ((u32)f2bf(od[qi][0] * linv[qi])) |
                   ((u32)f2bf(od[qi][1] * linv[qi]) << 16);
    const u32 p1 = ((u32)f2bf(od[qi][2] * linv[qi])) |
                   ((u32)f2bf(od[qi][3] * linv[qi]) << 16);
    u32x2 pk = {p0, p1};
    *(u32x2*)&O[row * D_MODEL + h * 64 + w * 16 + quad * 4] = pk;
  }
}

extern "C" void kernel_launch(void* const* d_in, const int* in_sizes, int n_in,
                              void* d_out, int out_size, void* d_ws, size_t ws_size,
                              hipStream_t stream) {
  const float* q  = (const float*)d_in[0];
  const float* k  = (const float*)d_in[1];
  const float* v  = (const float*)d_in[2];
  // d_in[3]: causal mask (tril) — semantics hardcoded in attn_causal
  const float* Wq = (const float*)d_in[4];
  const float* bq = (const float*)d_in[5];
  const float* Wk = (const float*)d_in[6];
  const float* bk = (const float*)d_in[7];
  const float* Wv = (const float*)d_in[8];
  const float* bv = (const float*)d_in[9];
  const float* Wo = (const float*)d_in[10];
  const float* bo = (const float*)d_in[11];
  float* out = (float*)d_out;

  const size_t NT = (size_t)MTOT * D_MODEL;
  const size_t NW = (size_t)D_MODEL * D_MODEL;

  u16* w0  = (u16*)d_ws;
  u16* qb  = w0;
  u16* kb  = w0 + NT;
  u16* vb  = w0 + 2 * NT;
  u16* Wqb = w0 + 3 * NT;
  u16* Wkb = Wqb + NW;
  u16* Wvb = Wqb + 2 * NW;
  u16* Wob = Wqb + 3 * NW;
  u16* Qp  = (u16*)d_out;        // d_out doubles as bf16 scratch until final GEMM
  u16* Kp  = (u16*)d_out + NT;
  u16* Vpt = qb;                 // qb dead after GEMM1 (VtX layout)
  u16* Xp  = kb;                 // kb dead after GEMM2

  const dim3 blk(256);

  CvtArgs ca;
  ca.s[0] = q;  ca.d[0] = qb;  ca.n[0] = (int)NT;
  ca.s[1] = k;  ca.d[1] = kb;  ca.n[1] = (int)NT;
  ca.s[2] = v;  ca.d[2] = vb;  ca.n[2] = (int)NT;
  ca.s[3] = Wq; ca.d[3] = Wqb; ca.n[3] = (int)NW;
  ca.s[4] = Wk; ca.d[4] = Wkb; ca.n[4] = (int)NW;
  ca.s[5] = Wv; ca.d[5] = Wvb; ca.n[5] = (int)NW;
  ca.s[6] = Wo; ca.d[6] = Wob; ca.n[6] = (int)NW;
  cvt_multi<<<dim3(4096, 7), blk, 0, stream>>>(ca);

  const dim3 ggrid(MTOT / 128, D_MODEL / 128);
  gemm_bt_bias<false, false><<<ggrid, blk, 0, stream>>>(qb, Wqb, bq, Qp);
  gemm_bt_bias<false, false><<<ggrid, blk, 0, stream>>>(kb, Wkb, bk, Kp);
  gemm_bt_bias<true,  false><<<ggrid, blk, 0, stream>>>(vb, Wvb, bv, Vpt);

  const dim3 agrid(4096);
  attn_causal<<<agrid, blk, 0, stream>>>(Qp, Kp, Vpt, Xp);

  gemm_bt_bias<false, true><<<ggrid, blk, 0, stream>>>(Xp, Wob, bo, out);
}

// Round 2
// 395.082 us; speedup vs baseline: 1.1284x; 1.1284x over previous
//
#include <hip/hip_runtime.h>
#include <hip/hip_bf16.h>
#include <stdint.h>

#define D_MODEL 1024
#define NUM_HEADS 16
#define DK 64
#define BATCH 4
#define SEQ 2048
#define MTOT (BATCH * SEQ)   // 8192 tokens

typedef unsigned short u16;
typedef unsigned int u32;
typedef __bf16 bf16x8 __attribute__((ext_vector_type(8)));
typedef float f32x4 __attribute__((ext_vector_type(4)));
typedef short s16x4 __attribute__((ext_vector_type(4)));
typedef int   i32x4 __attribute__((ext_vector_type(4)));
typedef int   i32x2 __attribute__((ext_vector_type(2)));
typedef uint  u32x2 __attribute__((ext_vector_type(2)));

// v_mfma_f32_16x16x16_bf16 (gfx90a+ "_1k" builtin name): A,B = 2 VGPRs (4 bf16), C/D = 4.
__device__ __forceinline__ f32x4 mfma16(s16x4 a, s16x4 b, f32x4 c) {
  return __builtin_amdgcn_mfma_f32_16x16x16bf16_1k(a, b, c, 0, 0, 0);
}

__device__ __forceinline__ u16 f2bf(float f) {
  union { float f; unsigned u; } c; c.f = f;
  unsigned u = c.u + 0x7fffu + ((c.u >> 16) & 1u);   // RNE
  return (u16)(u >> 16);
}
// pack two f32 into bf16x2 (truncate) — 1 instr
__device__ __forceinline__ u32 pack_bf2(float f0, float f1) {
  return __builtin_amdgcn_perm(__float_as_uint(f1), __float_as_uint(f0), 0x07060302u);
}
__device__ __forceinline__ s16x4 cast_s16x4(u32 lo, u32 hi) {
  u32x2 t = {lo, hi};
  return (s16x4)t;
}

// async global->LDS, 16B per lane (GEMM staging; LDS dst contiguous per wave).
__device__ __forceinline__ void async16(void* g, void* lds) {
  __builtin_amdgcn_global_load_lds(
      (__attribute__((address_space(1))) void*)g,
      (__attribute__((address_space(3))) void*)lds,
      16, 0, 0);
}

// ---------------- f32 -> bf16, all 7 tensors in one dispatch ----------------
struct CvtArgs {
  const float* s[7];
  u16* d[7];
  int n[7];
};
__global__ __launch_bounds__(256)
void cvt_multi(CvtArgs a) {
  const int which = blockIdx.y;
  const int n = a.n[which];
  const int i = (blockIdx.x * 256 + threadIdx.x) * 8;
  if (i >= n) return;
  const float* s = a.s[which];
  u16* d = a.d[which];
  const float4 x = *(const float4*)(s + i);
  const float4 y = *(const float4*)(s + i + 4);
  *(ushort4*)(d + i)     = make_ushort4(f2bf(x.x), f2bf(x.y), f2bf(x.z), f2bf(x.w));
  *(ushort4*)(d + i + 4) = make_ushort4(f2bf(y.x), f2bf(y.y), f2bf(y.z), f2bf(y.w));
}

// ---------------- GEMM: C = (A @ W^T + bias) * oscale (m97 structure) -------
// A:[M,1024] bf16, W:[1024,1024] bf16 ([n][k]), bias f32.
// oscale folds the attention 1/sqrt(dk)*log2e scale into the Q projection.
// VT_OUT: C -> VtX[b*1024 + chan][SEQ] bf16, key dim chunk-interleaved:
//         within each 32-key chunk, key kt*16+qd*4+j stored at pos qd*8+kt*4+j
//         (so one dwordx4 in attn yields both 16x16x16 A-frags).
// F32_OUT: C f32 [M,1024].
template <bool VT_OUT, bool F32_OUT>
__global__ __launch_bounds__(256, 2)
void gemm_bt_bias(const u16* __restrict__ A, const u16* __restrict__ W,
                  const float* __restrict__ bias, void* __restrict__ Cv,
                  float oscale)
{
  __shared__ u16 As[128 * 32];
  __shared__ u16 Bs[128 * 32];
  const int t = threadIdx.x;
  const int w = t >> 6, l = t & 63;
  const int quad = l >> 4, lane16 = l & 15;
  const int m0 = blockIdx.x * 128;
  const int n0 = blockIdx.y * 128;
  const int wm = (w >> 1) * 64, wn = (w & 1) * 64;

  const int srow = t >> 2;
  const int scol = (t & 3) * 8;
  const u16* Ag = A + (long)(m0 + srow) * D_MODEL + scol;
  const u16* Wg = W + (long)(n0 + srow) * D_MODEL + scol;
  u16* As_w = As + w * 512;
  u16* Bs_w = Bs + w * 512;

  f32x4 acc[4][4] = {};

  for (int k0 = 0; k0 < D_MODEL; k0 += 32) {
    __syncthreads();
    async16((void*)(Ag + k0), As_w);
    async16((void*)(Ag + 64 * D_MODEL + k0), As_w + 2048);
    async16((void*)(Wg + k0), Bs_w);
    async16((void*)(Wg + 64 * D_MODEL + k0), Bs_w + 2048);
    __syncthreads();

    bf16x8 af[4], bfr[4];
#pragma unroll
    for (int i = 0; i < 4; ++i)
      af[i] = *(const bf16x8*)&As[(wm + i * 16 + lane16) * 32 + quad * 8];
#pragma unroll
    for (int i = 0; i < 4; ++i)
      bfr[i] = *(const bf16x8*)&Bs[(wn + i * 16 + lane16) * 32 + quad * 8];
#pragma unroll
    for (int i = 0; i < 4; ++i)
#pragma unroll
      for (int jn = 0; jn < 4; ++jn)
        acc[i][jn] = __builtin_amdgcn_mfma_f32_16x16x32_bf16(af[i], bfr[jn], acc[i][jn], 0, 0, 0);
  }

  if constexpr (VT_OUT) {
    // restage through LDS: T[dk_local(0..127)][key_local(0..127)], pad to 132
    __shared__ u16 T[128 * 132];
#pragma unroll
    for (int jn = 0; jn < 4; ++jn) {
      const int col = wn + jn * 16 + lane16;          // dk_local
      const float bb = bias[n0 + col];
#pragma unroll
      for (int i = 0; i < 4; ++i) {
        const int rbase = wm + i * 16 + quad * 4;     // key_local
#pragma unroll
        for (int r = 0; r < 4; ++r)
          T[col * 132 + rbase + r] = f2bf((acc[i][jn][r] + bb) * oscale);
      }
    }
    __syncthreads();
    // coalesced, chunk-interleaved writeout: out pos 4a..4a+3 <- keys
    // (a>>3)*32 + ((a&7)>>1)*4 + (a&1)*16 + {0..3}
    const int bq = m0 >> 11, sbase = m0 & 2047;
    const int a = t & 31;
    const int keystart = ((a >> 3) * 32) + (((a & 7) >> 1) * 4) + ((a & 1) * 16);
    u16* orow = (u16*)Cv + ((long)bq * 1024 + n0) * SEQ + sbase + 4 * a;
#pragma unroll
    for (int pass = 0; pass < 16; ++pass) {
      const int dkl = (t >> 5) + 8 * pass;
      *(u32x2*)(orow + (long)dkl * SEQ) = *(const u32x2*)&T[dkl * 132 + keystart];
    }
  } else {
#pragma unroll
    for (int jn = 0; jn < 4; ++jn) {
      const int col = n0 + wn + jn * 16 + lane16;
      const float bb = bias[col];
#pragma unroll
      for (int i = 0; i < 4; ++i) {
        const int rbase = m0 + wm + i * 16 + quad * 4;
#pragma unroll
        for (int r = 0; r < 4; ++r) {
          const float v = (acc[i][jn][r] + bb) * oscale;
          if (F32_OUT) ((float*)Cv)[(long)(rbase + r) * D_MODEL + col] = v;
          else         ((u16*)Cv)[(long)(rbase + r) * D_MODEL + col] = f2bf(v);
        }
      }
    }
  }
}

// ---------------- Causal flash attention: split-K across the block ----------
// Block = 256 thr = 4 waves, owns ONE 32-row q-strip s. Wave w handles key
// chunks c = w, w+4, ... <= s (uniform ~ (s+1)/4 iterations per wave).
// Per-wave partial O^T / lsum merged via LDS (pure sums — no running max).
// Q comes PRE-SCALED by 1/sqrt(dk)*log2e (folded into the Q GEMM), so the
// softmax is a bare v_exp_f32. Diagonal chunk is peeled so the causal mask
// cndmasks exist only there. No K double-buffer: keeps natural VGPR ~118 so
// __launch_bounds__(256,3) never spills (round-1 lesson: the forced 128 cap
// spilled 32KB/block to scratch -> +128MB HBM writes).
// Merge LDS layout is b128 contiguous-across-lanes => bank-conflict-free.
// Grid: 4096 linear blocks; same-bh -> same XCD (id%8 round-robin), heavy
// strips first. Q,K: [B,S,D] bf16. VtX: chunk-interleaved. O: [B,S,D] bf16.
__global__ __launch_bounds__(256, 3)
void attn_causal(const u16* __restrict__ Q, const u16* __restrict__ K,
                 const u16* __restrict__ VtX, u16* __restrict__ O)
{
  __shared__ f32x4 mo[4][8][64];    // 32KB [wave][d*2+qi][lane] — conflict-free
  __shared__ float mls[4][2][64];   // 2KB  [wave][qi][lane]
  const int t = threadIdx.x;
  const int w = t >> 6, l = t & 63;
  const int quad = l >> 4, lane16 = l & 15;

  const int lin = blockIdx.x;        // 0..4095
  const int xcd = lin & 7;
  const int j = lin >> 3;
  const int bh = xcd * 8 + (j & 7);  // same bh -> same XCD (id%8 round-robin)
  const int s = 63 - (j >> 3);       // heavy strips first within each bh
  const int b = bh >> 4, h = bh & 15;
  const int qbase = s * 32;

  const long qkbase = (long)b * SEQ * D_MODEL + h * DK;

  // Q B-frags (x32): lane(q=lane16, quad) holds Q[q][ks*32+quad*8 ..+7]
  bf16x8 qf[2][2];
#pragma unroll
  for (int qi = 0; qi < 2; ++qi)
#pragma unroll
    for (int ks = 0; ks < 2; ++ks)
      qf[qi][ks] = *(const bf16x8*)&Q[qkbase +
          (long)(qbase + qi * 16 + lane16) * D_MODEL + ks * 32 + quad * 8];

  const u16* Kp = K + qkbase + (long)lane16 * D_MODEL + quad * 8;
  const u16* Vp = VtX + ((long)b * 1024 + h * 64 + lane16) * SEQ + quad * 8;

  f32x4 oacc[4][2] = {};     // [d][qi], O^T tiles (partial over this wave's chunks)
  float lsum[2] = {0.f, 0.f};

  auto body = [&](int c, bool diag) {
    // K A-frags (x32): lane(key=lane16, quad)
    bf16x8 kf[2][2];
#pragma unroll
    for (int kt = 0; kt < 2; ++kt)
#pragma unroll
      for (int ks = 0; ks < 2; ++ks)
        kf[kt][ks] = *(const bf16x8*)(Kp + (long)(c * 32 + kt * 16) * D_MODEL + ks * 32);
    // Vt A-frags: issue early so the load latency hides under QK+exp
    i32x4 vfd[4];
#pragma unroll
    for (int d = 0; d < 4; ++d)
      vfd[d] = *(const i32x4*)(Vp + (long)(d * 16) * SEQ + c * 32);

    // S^T = K·Q^T  (Q pre-scaled; result is log2-domain score)
    f32x4 st[2][2] = {};     // [kt][qi]
#pragma unroll
    for (int kt = 0; kt < 2; ++kt)
#pragma unroll
      for (int qi = 0; qi < 2; ++qi)
#pragma unroll
        for (int ks = 0; ks < 2; ++ks)
          st[kt][qi] = __builtin_amdgcn_mfma_f32_16x16x32_bf16(kf[kt][ks], qf[qi][ks], st[kt][qi], 0, 0, 0);

    // exp2 (raw v_exp_f32), causal mask only on the peeled diagonal chunk
    u32 pb[2][2][2];         // [kt][qi][pair]
#pragma unroll
    for (int kt = 0; kt < 2; ++kt)
#pragma unroll
      for (int qi = 0; qi < 2; ++qi) {
        float pv[4];
#pragma unroll
        for (int r = 0; r < 4; ++r) {
          float p = __builtin_amdgcn_exp2f(st[kt][qi][r]);
          if (diag && (kt * 16 + quad * 4 + r > qi * 16 + lane16)) p = 0.f;
          pv[r] = p;
        }
        lsum[qi] += (pv[0] + pv[1]) + (pv[2] + pv[3]);
        pb[kt][qi][0] = pack_bf2(pv[0], pv[1]);
        pb[kt][qi][1] = pack_bf2(pv[2], pv[3]);
      }

    // O^T += Vt·P^T  (x16; P^T B-frag = packed scores, layout identity)
#pragma unroll
    for (int d = 0; d < 4; ++d) {
      const s16x4 va0 = cast_s16x4((u32)vfd[d].x, (u32)vfd[d].y);
      const s16x4 va1 = cast_s16x4((u32)vfd[d].z, (u32)vfd[d].w);
#pragma unroll
      for (int qi = 0; qi < 2; ++qi) {
        const s16x4 pb0 = cast_s16x4(pb[0][qi][0], pb[0][qi][1]);
        const s16x4 pb1 = cast_s16x4(pb[1][qi][0], pb[1][qi][1]);
        oacc[d][qi] = mfma16(va0, pb0, oacc[d][qi]);
        oacc[d][qi] = mfma16(va1, pb1, oacc[d][qi]);
      }
    }
  };

  // wave w's chunks: c = w, w+4, ... <= s; diagonal (c==s) peeled.
  if (w <= s) {
    const int cl = s - ((s - w) & 3);   // largest c ≡ w (mod 4), c <= s
    for (int c = w; c < cl; c += 4) body(c, false);
    if (cl == s) body(cl, true);
    else         body(cl, false);
  }

  // ---- merge the 4 waves' partials via LDS (pure sum: no max tracking) ----
#pragma unroll
  for (int d = 0; d < 4; ++d)
#pragma unroll
    for (int qi = 0; qi < 2; ++qi)
      mo[w][d * 2 + qi][l] = oacc[d][qi];
  mls[w][0][l] = lsum[0];
  mls[w][1][l] = lsum[1];
  __syncthreads();

  // wave w owns output d-tile d=w: sum the 4 partials (b128 contiguous reads)
  f32x4 od[2] = {};
  float ls0 = 0.f, ls1 = 0.f;
#pragma unroll
  for (int ww = 0; ww < 4; ++ww) {
    od[0] += mo[ww][w * 2 + 0][l];
    od[1] += mo[ww][w * 2 + 1][l];
    ls0 += mls[ww][0][l];
    ls1 += mls[ww][1][l];
  }
  float linv[2];
  {
    float v0 = ls0;
    v0 += __shfl_xor(v0, 16); v0 += __shfl_xor(v0, 32);
    linv[0] = 1.f / v0;
    float v1 = ls1;
    v1 += __shfl_xor(v1, 16); v1 += __shfl_xor(v1, 32);
    linv[1] = 1.f / v1;
  }

  // epilogue: O[q][dk] = od^T / l ; lane writes 4 consecutive dk as b64
#pragma unroll
  for (int qi = 0; qi < 2; ++qi) {
    const long row = (long)b * SEQ + qbase + qi * 16 + lane16;
    const u32 p0 = ((u32)f2bf(od[qi][0] * linv[qi])) |
                   ((u32)f2bf(od[qi][1] * linv[qi]) << 16);
    const u32 p1 = ((u32)f2bf(od[qi][2] * linv[qi])) |
                   ((u32)f2bf(od[qi][3] * linv[qi]) << 16);
    u32x2 pk = {p0, p1};
    *(u32x2*)&O[row * D_MODEL + h * 64 + w * 16 + quad * 4] = pk;
  }
}

extern "C" void kernel_launch(void* const* d_in, const int* in_sizes, int n_in,
                              void* d_out, int out_size, void* d_ws, size_t ws_size,
                              hipStream_t stream) {
  const float* q  = (const float*)d_in[0];
  const float* k  = (const float*)d_in[1];
  const float* v  = (const float*)d_in[2];
  // d_in[3]: causal mask (tril) — semantics hardcoded in attn_causal
  const float* Wq = (const float*)d_in[4];
  const float* bq = (const float*)d_in[5];
  const float* Wk = (const float*)d_in[6];
  const float* bk = (const float*)d_in[7];
  const float* Wv = (const float*)d_in[8];
  const float* bv = (const float*)d_in[9];
  const float* Wo = (const float*)d_in[10];
  const float* bo = (const float*)d_in[11];
  float* out = (float*)d_out;

  const size_t NT = (size_t)MTOT * D_MODEL;
  const size_t NW = (size_t)D_MODEL * D_MODEL;

  u16* w0  = (u16*)d_ws;
  u16* qb  = w0;
  u16* kb  = w0 + NT;
  u16* vb  = w0 + 2 * NT;
  u16* Wqb = w0 + 3 * NT;
  u16* Wkb = Wqb + NW;
  u16* Wvb = Wqb + 2 * NW;
  u16* Wob = Wqb + 3 * NW;
  u16* Qp  = (u16*)d_out;        // d_out doubles as bf16 scratch until final GEMM
  u16* Kp  = (u16*)d_out + NT;
  u16* Vpt = qb;                 // qb dead after GEMM1 (VtX layout)
  u16* Xp  = kb;                 // kb dead after GEMM2

  const dim3 blk(256);

  CvtArgs ca;
  ca.s[0] = q;  ca.d[0] = qb;  ca.n[0] = (int)NT;
  ca.s[1] = k;  ca.d[1] = kb;  ca.n[1] = (int)NT;
  ca.s[2] = v;  ca.d[2] = vb;  ca.n[2] = (int)NT;
  ca.s[3] = Wq; ca.d[3] = Wqb; ca.n[3] = (int)NW;
  ca.s[4] = Wk; ca.d[4] = Wkb; ca.n[4] = (int)NW;
  ca.s[5] = Wv; ca.d[5] = Wvb; ca.n[5] = (int)NW;
  ca.s[6] = Wo; ca.d[6] = Wob; ca.n[6] = (int)NW;
  cvt_multi<<<dim3(4096, 7), blk, 0, stream>>>(ca);

  const float SC = 0.125f * 1.4426950408889634f;   // 1/sqrt(dk) * log2(e)
  const dim3 ggrid(MTOT / 128, D_MODEL / 128);
  gemm_bt_bias<false, false><<<ggrid, blk, 0, stream>>>(qb, Wqb, bq, Qp, SC);
  gemm_bt_bias<false, false><<<ggrid, blk, 0, stream>>>(kb, Wkb, bk, Kp, 1.f);
  gemm_bt_bias<true,  false><<<ggrid, blk, 0, stream>>>(vb, Wvb, bv, Vpt, 1.f);

  const dim3 agrid(4096);
  attn_causal<<<agrid, blk, 0, stream>>>(Qp, Kp, Vpt, Xp);

  gemm_bt_bias<false, true><<<ggrid, blk, 0, stream>>>(Xp, Wob, bo, out, 1.f);
}

// Round 3
// 316.273 us; speedup vs baseline: 1.4095x; 1.2492x over previous
//
#include <hip/hip_runtime.h>
#include <hip/hip_bf16.h>
#include <stdint.h>

#define D_MODEL 1024
#define NUM_HEADS 16
#define DK 64
#define BATCH 4
#define SEQ 2048
#define MTOT (BATCH * SEQ)   // 8192 tokens

typedef unsigned short u16;
typedef unsigned int u32;
typedef __bf16 bf16x8 __attribute__((ext_vector_type(8)));
typedef float f32x4 __attribute__((ext_vector_type(4)));
typedef short s16x4 __attribute__((ext_vector_type(4)));
typedef int   i32x4 __attribute__((ext_vector_type(4)));
typedef int   i32x2 __attribute__((ext_vector_type(2)));
typedef uint  u32x2 __attribute__((ext_vector_type(2)));

// v_mfma_f32_16x16x16_bf16 (gfx90a+ "_1k" builtin name): A,B = 2 VGPRs (4 bf16), C/D = 4.
__device__ __forceinline__ f32x4 mfma16(s16x4 a, s16x4 b, f32x4 c) {
  return __builtin_amdgcn_mfma_f32_16x16x16bf16_1k(a, b, c, 0, 0, 0);
}

__device__ __forceinline__ u16 f2bf(float f) {
  union { float f; unsigned u; } c; c.f = f;
  unsigned u = c.u + 0x7fffu + ((c.u >> 16) & 1u);   // RNE
  return (u16)(u >> 16);
}
// pack two f32 into bf16x2 (truncate) — 1 instr
__device__ __forceinline__ u32 pack_bf2(float f0, float f1) {
  return __builtin_amdgcn_perm(__float_as_uint(f1), __float_as_uint(f0), 0x07060302u);
}
__device__ __forceinline__ s16x4 cast_s16x4(u32 lo, u32 hi) {
  u32x2 t = {lo, hi};
  return (s16x4)t;
}

// async global->LDS, 16B per lane (GEMM staging; LDS dst contiguous per wave).
__device__ __forceinline__ void async16(void* g, void* lds) {
  __builtin_amdgcn_global_load_lds(
      (__attribute__((address_space(1))) void*)g,
      (__attribute__((address_space(3))) void*)lds,
      16, 0, 0);
}

// ---------------- f32 -> bf16, all 7 tensors in one dispatch ----------------
struct CvtArgs {
  const float* s[7];
  u16* d[7];
  int n[7];
};
__global__ __launch_bounds__(256)
void cvt_multi(CvtArgs a) {
  const int which = blockIdx.y;
  const int n = a.n[which];
  const int i = (blockIdx.x * 256 + threadIdx.x) * 8;
  if (i >= n) return;
  const float* s = a.s[which];
  u16* d = a.d[which];
  const float4 x = *(const float4*)(s + i);
  const float4 y = *(const float4*)(s + i + 4);
  *(ushort4*)(d + i)     = make_ushort4(f2bf(x.x), f2bf(x.y), f2bf(x.z), f2bf(x.w));
  *(ushort4*)(d + i + 4) = make_ushort4(f2bf(y.x), f2bf(y.y), f2bf(y.z), f2bf(y.w));
}

// ---------------- GEMM: C = (A @ W^T + bias) * oscale (m97 structure) -------
// A:[M,1024] bf16, W:[1024,1024] bf16 ([n][k]), bias f32.
// oscale folds the attention 1/sqrt(dk)*log2e scale into the Q projection.
// VT_OUT: C -> VtX[b*1024 + chan][SEQ] bf16, key dim chunk-interleaved:
//         within each 32-key chunk, key kt*16+qd*4+j stored at pos qd*8+kt*4+j
//         (so one dwordx4 in attn yields both 16x16x16 A-frags).
// F32_OUT: C f32 [M,1024].
template <bool VT_OUT, bool F32_OUT>
__global__ __launch_bounds__(256, 2)
void gemm_bt_bias(const u16* __restrict__ A, const u16* __restrict__ W,
                  const float* __restrict__ bias, void* __restrict__ Cv,
                  float oscale)
{
  __shared__ u16 As[128 * 32];
  __shared__ u16 Bs[128 * 32];
  const int t = threadIdx.x;
  const int w = t >> 6, l = t & 63;
  const int quad = l >> 4, lane16 = l & 15;
  const int m0 = blockIdx.x * 128;
  const int n0 = blockIdx.y * 128;
  const int wm = (w >> 1) * 64, wn = (w & 1) * 64;

  const int srow = t >> 2;
  const int scol = (t & 3) * 8;
  const u16* Ag = A + (long)(m0 + srow) * D_MODEL + scol;
  const u16* Wg = W + (long)(n0 + srow) * D_MODEL + scol;
  u16* As_w = As + w * 512;
  u16* Bs_w = Bs + w * 512;

  f32x4 acc[4][4] = {};

  for (int k0 = 0; k0 < D_MODEL; k0 += 32) {
    __syncthreads();
    async16((void*)(Ag + k0), As_w);
    async16((void*)(Ag + 64 * D_MODEL + k0), As_w + 2048);
    async16((void*)(Wg + k0), Bs_w);
    async16((void*)(Wg + 64 * D_MODEL + k0), Bs_w + 2048);
    __syncthreads();

    bf16x8 af[4], bfr[4];
#pragma unroll
    for (int i = 0; i < 4; ++i)
      af[i] = *(const bf16x8*)&As[(wm + i * 16 + lane16) * 32 + quad * 8];
#pragma unroll
    for (int i = 0; i < 4; ++i)
      bfr[i] = *(const bf16x8*)&Bs[(wn + i * 16 + lane16) * 32 + quad * 8];
#pragma unroll
    for (int i = 0; i < 4; ++i)
#pragma unroll
      for (int jn = 0; jn < 4; ++jn)
        acc[i][jn] = __builtin_amdgcn_mfma_f32_16x16x32_bf16(af[i], bfr[jn], acc[i][jn], 0, 0, 0);
  }

  if constexpr (VT_OUT) {
    // restage through LDS: T[dk_local(0..127)][key_local(0..127)], pad to 132
    __shared__ u16 T[128 * 132];
#pragma unroll
    for (int jn = 0; jn < 4; ++jn) {
      const int col = wn + jn * 16 + lane16;          // dk_local
      const float bb = bias[n0 + col];
#pragma unroll
      for (int i = 0; i < 4; ++i) {
        const int rbase = wm + i * 16 + quad * 4;     // key_local
#pragma unroll
        for (int r = 0; r < 4; ++r)
          T[col * 132 + rbase + r] = f2bf((acc[i][jn][r] + bb) * oscale);
      }
    }
    __syncthreads();
    // coalesced, chunk-interleaved writeout: out pos 4a..4a+3 <- keys
    // (a>>3)*32 + ((a&7)>>1)*4 + (a&1)*16 + {0..3}
    const int bq = m0 >> 11, sbase = m0 & 2047;
    const int a = t & 31;
    const int keystart = ((a >> 3) * 32) + (((a & 7) >> 1) * 4) + ((a & 1) * 16);
    u16* orow = (u16*)Cv + ((long)bq * 1024 + n0) * SEQ + sbase + 4 * a;
#pragma unroll
    for (int pass = 0; pass < 16; ++pass) {
      const int dkl = (t >> 5) + 8 * pass;
      *(u32x2*)(orow + (long)dkl * SEQ) = *(const u32x2*)&T[dkl * 132 + keystart];
    }
  } else {
#pragma unroll
    for (int jn = 0; jn < 4; ++jn) {
      const int col = n0 + wn + jn * 16 + lane16;
      const float bb = bias[col];
#pragma unroll
      for (int i = 0; i < 4; ++i) {
        const int rbase = m0 + wm + i * 16 + quad * 4;
#pragma unroll
        for (int r = 0; r < 4; ++r) {
          const float v = (acc[i][jn][r] + bb) * oscale;
          if (F32_OUT) ((float*)Cv)[(long)(rbase + r) * D_MODEL + col] = v;
          else         ((u16*)Cv)[(long)(rbase + r) * D_MODEL + col] = f2bf(v);
        }
      }
    }
  }
}

// ---------------- Causal flash attention: LDS-staged K/V, 4 strips/block ----
// Block = 4 waves; wave w owns strip sw = 4g+w (32 q-rows), full accumulator,
// NO merge. K/V chunk tiles staged in LDS once per block and consumed by all
// 4 waves (L2 traffic /3.8 vs split-K: 1.09GB -> 285MB). Double-buffered,
// reg-staged (global->reg->ds_write), loads issued a full compute phase ahead
// of their barrier so the __syncthreads vmcnt drain is cheap (T14).
// LDS padded: K [32][72] u16 (144B rows), V [64][40] u16 (80B rows) — both
// verified bank-uniform for the b128 frag reads AND the staging writes.
// Chunk count per block = 4(g+1) (always even -> clean 2-chunk unroll, all
// reg buffers statically named). Barriers are block-uniform; compute guarded
// per-wave by c <= sw; causal mask only on the peeled diagonal (c == sw).
// Q pre-scaled by 1/sqrt(dk)*log2e (folded into Q GEMM) -> bare v_exp_f32.
// Grid: 1024 blocks; same-bh -> same XCD (id%8 round-robin), heavy-g first.
// Q,K: [B,S,D] bf16. VtX: chunk-interleaved [b*1024+chan][SEQ]. O: bf16.
__global__ __launch_bounds__(256, 3)
void attn_causal(const u16* __restrict__ Q, const u16* __restrict__ K,
                 const u16* __restrict__ VtX, u16* __restrict__ O)
{
  __shared__ __align__(16) u16 Kb[2][32][72];   // 9216B  (padded 128B->144B rows)
  __shared__ __align__(16) u16 Vb[2][64][40];   // 10240B (padded 64B->80B rows)
  const int t = threadIdx.x;
  const int w = t >> 6, l = t & 63;
  const int quad = l >> 4, lane16 = l & 15;

  const int lin = blockIdx.x;        // 0..1023
  const int xcd = lin & 7;
  const int j = lin >> 3;            // 0..127
  const int bh = xcd * 8 + (j & 7);  // same bh -> same XCD (id%8 round-robin)
  const int g = 15 - (j >> 3);       // 0..15, heavy blocks first
  const int b = bh >> 4, h = bh & 15;
  const int sw = 4 * g + w;          // this wave's strip (32 q-rows)
  const int cmax = 4 * g + 3;        // last chunk any wave in block needs
  const int qbase = sw * 32;

  const long qkbase = (long)b * SEQ * D_MODEL + h * DK;

  // Q B-frags (x32): lane(q=lane16, quad) holds Q[q][ks*32+quad*8 ..+7]
  bf16x8 qf[2][2];
#pragma unroll
  for (int qi = 0; qi < 2; ++qi)
#pragma unroll
    for (int ks = 0; ks < 2; ++ks)
      qf[qi][ks] = *(const bf16x8*)&Q[qkbase +
          (long)(qbase + qi * 16 + lane16) * D_MODEL + ks * 32 + quad * 8];

  // staging addresses: K chunk = 32 rows x 128B slice; V chunk = 64 rows x 64B
  const int krow = t >> 3, kc = t & 7;          // 256 thr: 32 rows x 8 cols
  const char* Kgt = (const char*)(K + qkbase) + (long)krow * (D_MODEL * 2) + kc * 16;
  u16* KbD0 = &Kb[0][krow][kc * 8];
  u16* KbD1 = &Kb[1][krow][kc * 8];
  const int vrow = t >> 2, vc = t & 3;          // 256 thr: 64 rows x 4 cols
  const char* Vgt = (const char*)(VtX + ((long)b * 1024 + h * 64) * SEQ) +
                    (long)vrow * (SEQ * 2) + vc * 16;
  u16* VbD0 = &Vb[0][vrow][vc * 8];
  u16* VbD1 = &Vb[1][vrow][vc * 8];

  f32x4 oacc[4][2] = {};     // [d][qi], O^T tiles for this wave's strip
  float lsum[2] = {0.f, 0.f};

  auto body = [&](const u16 (*Kbuf)[72], const u16 (*Vbuf)[40], bool diag) {
    // K A-frags from LDS: lane(key=lane16, quad)
    bf16x8 kf[2][2];
#pragma unroll
    for (int kt = 0; kt < 2; ++kt)
#pragma unroll
      for (int ks = 0; ks < 2; ++ks)
        kf[kt][ks] = *(const bf16x8*)&Kbuf[kt * 16 + lane16][ks * 32 + quad * 8];
    // Vt A-frags from LDS
    i32x4 vfd[4];
#pragma unroll
    for (int d = 0; d < 4; ++d)
      vfd[d] = *(const i32x4*)&Vbuf[d * 16 + lane16][quad * 8];

    // S^T = K·Q^T  (Q pre-scaled; result is log2-domain score)
    f32x4 st[2][2] = {};     // [kt][qi]
#pragma unroll
    for (int kt = 0; kt < 2; ++kt)
#pragma unroll
      for (int qi = 0; qi < 2; ++qi)
#pragma unroll
        for (int ks = 0; ks < 2; ++ks)
          st[kt][qi] = __builtin_amdgcn_mfma_f32_16x16x32_bf16(kf[kt][ks], qf[qi][ks], st[kt][qi], 0, 0, 0);

    // exp2 (raw v_exp_f32), causal mask only on the peeled diagonal chunk
    u32 pb[2][2][2];         // [kt][qi][pair]
#pragma unroll
    for (int kt = 0; kt < 2; ++kt)
#pragma unroll
      for (int qi = 0; qi < 2; ++qi) {
        float pv[4];
#pragma unroll
        for (int r = 0; r < 4; ++r) {
          float p = __builtin_amdgcn_exp2f(st[kt][qi][r]);
          if (diag && (kt * 16 + quad * 4 + r > qi * 16 + lane16)) p = 0.f;
          pv[r] = p;
        }
        lsum[qi] += (pv[0] + pv[1]) + (pv[2] + pv[3]);
        pb[kt][qi][0] = pack_bf2(pv[0], pv[1]);
        pb[kt][qi][1] = pack_bf2(pv[2], pv[3]);
      }

    // O^T += Vt·P^T  (x16; P^T B-frag = packed scores, layout identity)
#pragma unroll
    for (int d = 0; d < 4; ++d) {
      const s16x4 va0 = cast_s16x4((u32)vfd[d].x, (u32)vfd[d].y);
      const s16x4 va1 = cast_s16x4((u32)vfd[d].z, (u32)vfd[d].w);
#pragma unroll
      for (int qi = 0; qi < 2; ++qi) {
        const s16x4 pb0 = cast_s16x4(pb[0][qi][0], pb[0][qi][1]);
        const s16x4 pb1 = cast_s16x4(pb[1][qi][0], pb[1][qi][1]);
        oacc[d][qi] = mfma16(va0, pb0, oacc[d][qi]);
        oacc[d][qi] = mfma16(va1, pb1, oacc[d][qi]);
      }
    }
  };

  // ---- staged chunk loop (chunks 0..cmax, count = 4(g+1), even) ----
  // K chunk byte stride: 32 rows * 2048B = 65536; V chunk byte stride: 64.
  {
    // prologue: stage chunk 0, prefetch chunks 1,2 into regs
    i32x4 a0 = *(const i32x4*)(Kgt);
    i32x4 a1 = *(const i32x4*)(Vgt);
    *(i32x4*)KbD0 = a0;
    *(i32x4*)VbD0 = a1;
  }
  i32x4 gKA = *(const i32x4*)(Kgt + 65536);
  i32x4 gVA = *(const i32x4*)(Vgt + 64);
  i32x4 gKB = *(const i32x4*)(Kgt + 2 * 65536);
  i32x4 gVB = *(const i32x4*)(Vgt + 2 * 64);
  __syncthreads();

  for (int c = 0; c <= cmax; c += 2) {
    // state: buf0 = chunk c (ready); gA = c+1; gB = c+2 (if exists)
    *(i32x4*)KbD1 = gKA;
    *(i32x4*)VbD1 = gVA;
    if (c + 3 <= cmax) {
      gKA = *(const i32x4*)(Kgt + (long)(c + 3) * 65536);
      gVA = *(const i32x4*)(Vgt + (long)(c + 3) * 64);
    }
    if (c <= sw) body(Kb[0], Vb[0], c == sw);
    __syncthreads();                  // buf1 (chunk c+1) ready
    if (c + 2 <= cmax) {
      *(i32x4*)KbD0 = gKB;
      *(i32x4*)VbD0 = gVB;
      if (c + 4 <= cmax) {
        gKB = *(const i32x4*)(Kgt + (long)(c + 4) * 65536);
        gVB = *(const i32x4*)(Vgt + (long)(c + 4) * 64);
      }
    }
    if (c + 1 <= sw) body(Kb[1], Vb[1], (c + 1) == sw);
    __syncthreads();                  // buf0 (chunk c+2) ready
  }

  // ---- softmax denominator: reduce lsum across quads, then epilogue ----
  float linv[2];
#pragma unroll
  for (int qi = 0; qi < 2; ++qi) {
    float v = lsum[qi];
    v += __shfl_xor(v, 16);
    v += __shfl_xor(v, 32);
    linv[qi] = 1.f / v;
  }

  // epilogue: O[q][dk] = oacc^T / l ; lane writes 4 consecutive dk as b64
#pragma unroll
  for (int qi = 0; qi < 2; ++qi) {
    const long row = (long)b * SEQ + qbase + qi * 16 + lane16;
#pragma unroll
    for (int d = 0; d < 4; ++d) {
      const u32 p0 = ((u32)f2bf(oacc[d][qi][0] * linv[qi])) |
                     ((u32)f2bf(oacc[d][qi][1] * linv[qi]) << 16);
      const u32 p1 = ((u32)f2bf(oacc[d][qi][2] * linv[qi])) |
                     ((u32)f2bf(oacc[d][qi][3] * linv[qi]) << 16);
      u32x2 pk = {p0, p1};
      *(u32x2*)&O[row * D_MODEL + h * 64 + d * 16 + quad * 4] = pk;
    }
  }
}

extern "C" void kernel_launch(void* const* d_in, const int* in_sizes, int n_in,
                              void* d_out, int out_size, void* d_ws, size_t ws_size,
                              hipStream_t stream) {
  const float* q  = (const float*)d_in[0];
  const float* k  = (const float*)d_in[1];
  const float* v  = (const float*)d_in[2];
  // d_in[3]: causal mask (tril) — semantics hardcoded in attn_causal
  const float* Wq = (const float*)d_in[4];
  const float* bq = (const float*)d_in[5];
  const float* Wk = (const float*)d_in[6];
  const float* bk = (const float*)d_in[7];
  const float* Wv = (const float*)d_in[8];
  const float* bv = (const float*)d_in[9];
  const float* Wo = (const float*)d_in[10];
  const float* bo = (const float*)d_in[11];
  float* out = (float*)d_out;

  const size_t NT = (size_t)MTOT * D_MODEL;
  const size_t NW = (size_t)D_MODEL * D_MODEL;

  u16* w0  = (u16*)d_ws;
  u16* qb  = w0;
  u16* kb  = w0 + NT;
  u16* vb  = w0 + 2 * NT;
  u16* Wqb = w0 + 3 * NT;
  u16* Wkb = Wqb + NW;
  u16* Wvb = Wqb + 2 * NW;
  u16* Wob = Wqb + 3 * NW;
  u16* Qp  = (u16*)d_out;        // d_out doubles as bf16 scratch until final GEMM
  u16* Kp  = (u16*)d_out + NT;
  u16* Vpt = qb;                 // qb dead after GEMM1 (VtX layout)
  u16* Xp  = kb;                 // kb dead after GEMM2

  const dim3 blk(256);

  CvtArgs ca;
  ca.s[0] = q;  ca.d[0] = qb;  ca.n[0] = (int)NT;
  ca.s[1] = k;  ca.d[1] = kb;  ca.n[1] = (int)NT;
  ca.s[2] = v;  ca.d[2] = vb;  ca.n[2] = (int)NT;
  ca.s[3] = Wq; ca.d[3] = Wqb; ca.n[3] = (int)NW;
  ca.s[4] = Wk; ca.d[4] = Wkb; ca.n[4] = (int)NW;
  ca.s[5] = Wv; ca.d[5] = Wvb; ca.n[5] = (int)NW;
  ca.s[6] = Wo; ca.d[6] = Wob; ca.n[6] = (int)NW;
  cvt_multi<<<dim3(4096, 7), blk, 0, stream>>>(ca);

  const float SC = 0.125f * 1.4426950408889634f;   // 1/sqrt(dk) * log2(e)
  const dim3 ggrid(MTOT / 128, D_MODEL / 128);
  gemm_bt_bias<false, false><<<ggrid, blk, 0, stream>>>(qb, Wqb, bq, Qp, SC);
  gemm_bt_bias<false, false><<<ggrid, blk, 0, stream>>>(kb, Wkb, bk, Kp, 1.f);
  gemm_bt_bias<true,  false><<<ggrid, blk, 0, stream>>>(vb, Wvb, bv, Vpt, 1.f);

  const dim3 agrid(1024);
  attn_causal<<<agrid, blk, 0, stream>>>(Qp, Kp, Vpt, Xp);

  gemm_bt_bias<false, true><<<ggrid, blk, 0, stream>>>(Xp, Wob, bo, out, 1.f);
}

// Round 6
// 316.075 us; speedup vs baseline: 1.4104x; 1.0006x over previous
//
#include <hip/hip_runtime.h>
#include <hip/hip_bf16.h>
#include <stdint.h>

#define D_MODEL 1024
#define NUM_HEADS 16
#define DK 64
#define BATCH 4
#define SEQ 2048
#define MTOT (BATCH * SEQ)   // 8192 tokens

typedef unsigned short u16;
typedef unsigned int u32;
typedef __bf16 bf16x8 __attribute__((ext_vector_type(8)));
typedef float f32x4 __attribute__((ext_vector_type(4)));
typedef short s16x4 __attribute__((ext_vector_type(4)));
typedef int   i32x4 __attribute__((ext_vector_type(4)));
typedef int   i32x2 __attribute__((ext_vector_type(2)));
typedef uint  u32x2 __attribute__((ext_vector_type(2)));

// v_mfma_f32_16x16x16_bf16 (gfx90a+ "_1k" builtin name): A,B = 2 VGPRs (4 bf16), C/D = 4.
__device__ __forceinline__ f32x4 mfma16(s16x4 a, s16x4 b, f32x4 c) {
  return __builtin_amdgcn_mfma_f32_16x16x16bf16_1k(a, b, c, 0, 0, 0);
}

__device__ __forceinline__ u16 f2bf(float f) {
  union { float f; unsigned u; } c; c.f = f;
  unsigned u = c.u + 0x7fffu + ((c.u >> 16) & 1u);   // RNE
  return (u16)(u >> 16);
}
// pack two f32 into bf16x2 (truncate) — 1 instr
__device__ __forceinline__ u32 pack_bf2(float f0, float f1) {
  return __builtin_amdgcn_perm(__float_as_uint(f1), __float_as_uint(f0), 0x07060302u);
}
__device__ __forceinline__ s16x4 cast_s16x4(u32 lo, u32 hi) {
  u32x2 t = {lo, hi};
  return (s16x4)t;
}

// async global->LDS, 16B per lane (GEMM staging; LDS dst contiguous per wave).
__device__ __forceinline__ void async16(void* g, void* lds) {
  __builtin_amdgcn_global_load_lds(
      (__attribute__((address_space(1))) void*)g,
      (__attribute__((address_space(3))) void*)lds,
      16, 0, 0);
}
// explicit drain of outstanding global/buffer ops (defensive: __syncthreads
// already implies this per the compiler's barrier lowering, but make the
// double-buffer's correctness independent of that).
__device__ __forceinline__ void vm_drain() {
  asm volatile("s_waitcnt vmcnt(0)" ::: "memory");
}

// ---------------- f32 -> bf16, all 7 tensors in one dispatch ----------------
struct CvtArgs {
  const float* s[7];
  u16* d[7];
  int n[7];
};
__global__ __launch_bounds__(256)
void cvt_multi(CvtArgs a) {
  const int which = blockIdx.y;
  const int n = a.n[which];
  const int i = (blockIdx.x * 256 + threadIdx.x) * 8;
  if (i >= n) return;
  const float* s = a.s[which];
  u16* d = a.d[which];
  const float4 x = *(const float4*)(s + i);
  const float4 y = *(const float4*)(s + i + 4);
  *(ushort4*)(d + i)     = make_ushort4(f2bf(x.x), f2bf(x.y), f2bf(x.z), f2bf(x.w));
  *(ushort4*)(d + i + 4) = make_ushort4(f2bf(y.x), f2bf(y.y), f2bf(y.z), f2bf(y.w));
}

// ---------------- GEMM: C = (A @ W^T + bias) * oscale -----------------------
// m97 tile (128x128, BK=32), DOUBLE-BUFFERED LDS, stage issued BEFORE the
// compute phase, ONE barrier per K-step (T3-minimum recipe): the barrier's
// vmcnt(0) drain lands ~16 MFMA + 8 ds_read after issue, so the global->LDS
// latency (round-3 bottleneck: zero overlap) hides under compute.
// LDS: 2x(As+Bs)=32KB; VT restage buffer T (33KB) UNIONED over the same smem
// (only used post-loop) -> 33KB, 2 blocks/CU.
// Batched: grid.z picks per-tensor pointers (QKV in one dispatch).
// mode 0: C bf16 [M,1024].  mode 2: C f32 [M,1024].
// mode 1 (VT): C -> VtX[b*1024+chan][SEQ] bf16, key dim chunk-interleaved:
//   within each 32-key chunk, key kt*16+qd*4+j stored at pos qd*8+kt*4+j.
struct GBatch {
  const u16* A[3]; const u16* W[3]; const float* bias[3];
  void* C[3]; float osc[3]; int mode[3];
};
__global__ __launch_bounds__(256, 2)
void gemm_bt_bias(GBatch ga)
{
  __shared__ __align__(16) u16 smem[16896];   // max(4*4096 dbuf, 128*132 T)
  u16* As0 = smem;
  u16* Bs0 = smem + 4096;
  u16* As1 = smem + 8192;
  u16* Bs1 = smem + 12288;

  const int z = blockIdx.z;
  const u16* __restrict__ A = ga.A[z];
  const u16* __restrict__ W = ga.W[z];
  const float* __restrict__ bias = ga.bias[z];
  void* __restrict__ Cv = ga.C[z];
  const float oscale = ga.osc[z];
  const int mode = ga.mode[z];

  const int t = threadIdx.x;
  const int w = t >> 6, l = t & 63;
  const int quad = l >> 4, lane16 = l & 15;
  const int m0 = blockIdx.x * 128;
  const int n0 = blockIdx.y * 128;
  const int wm = (w >> 1) * 64, wn = (w & 1) * 64;

  const int srow = t >> 2;
  const int scol = (t & 3) * 8;
  const u16* Ag = A + (long)(m0 + srow) * D_MODEL + scol;
  const u16* Wg = W + (long)(n0 + srow) * D_MODEL + scol;

  f32x4 acc[4][4] = {};

  auto stage = [&](u16* As_, u16* Bs_, int k0) {
    async16((void*)(Ag + k0), As_ + w * 512);
    async16((void*)(Ag + 64 * D_MODEL + k0), As_ + w * 512 + 2048);
    async16((void*)(Wg + k0), Bs_ + w * 512);
    async16((void*)(Wg + 64 * D_MODEL + k0), Bs_ + w * 512 + 2048);
  };
  auto compute = [&](const u16* As_, const u16* Bs_) {
    bf16x8 af[4], bfr[4];
#pragma unroll
    for (int i = 0; i < 4; ++i)
      af[i] = *(const bf16x8*)&As_[(wm + i * 16 + lane16) * 32 + quad * 8];
#pragma unroll
    for (int i = 0; i < 4; ++i)
      bfr[i] = *(const bf16x8*)&Bs_[(wn + i * 16 + lane16) * 32 + quad * 8];
#pragma unroll
    for (int i = 0; i < 4; ++i)
#pragma unroll
      for (int jn = 0; jn < 4; ++jn)
        acc[i][jn] = __builtin_amdgcn_mfma_f32_16x16x32_bf16(af[i], bfr[jn], acc[i][jn], 0, 0, 0);
  };

  // prologue: buf0 <- k=0
  stage(As0, Bs0, 0);
  vm_drain();
  __syncthreads();
#pragma unroll 1
  for (int k0 = 0; k0 < D_MODEL; k0 += 64) {
    stage(As1, Bs1, k0 + 32);                  // k0+32 <= 992, always valid
    compute(As0, Bs0);
    vm_drain();
    __syncthreads();                           // buf1 ready; buf0 free
    if (k0 + 64 < D_MODEL) stage(As0, Bs0, k0 + 64);
    compute(As1, Bs1);
    vm_drain();
    __syncthreads();                           // buf0 ready; buf1 free
  }

  if (mode == 1) {
    // restage through LDS (reuses smem — main loop done): T[dk][key], pad 132
    u16* T = smem;
#pragma unroll
    for (int jn = 0; jn < 4; ++jn) {
      const int col = wn + jn * 16 + lane16;          // dk_local
      const float bb = bias[n0 + col];
#pragma unroll
      for (int i = 0; i < 4; ++i) {
        const int rbase = wm + i * 16 + quad * 4;     // key_local
#pragma unroll
        for (int r = 0; r < 4; ++r)
          T[col * 132 + rbase + r] = f2bf((acc[i][jn][r] + bb) * oscale);
      }
    }
    __syncthreads();
    // coalesced, chunk-interleaved writeout: out pos 4a..4a+3 <- keys
    // (a>>3)*32 + ((a&7)>>1)*4 + (a&1)*16 + {0..3}
    const int bq = m0 >> 11, sbase = m0 & 2047;
    const int a = t & 31;
    const int keystart = ((a >> 3) * 32) + (((a & 7) >> 1) * 4) + ((a & 1) * 16);
    u16* orow = (u16*)Cv + ((long)bq * 1024 + n0) * SEQ + sbase + 4 * a;
#pragma unroll
    for (int pass = 0; pass < 16; ++pass) {
      const int dkl = (t >> 5) + 8 * pass;
      *(u32x2*)(orow + (long)dkl * SEQ) = *(const u32x2*)&T[dkl * 132 + keystart];
    }
  } else {
#pragma unroll
    for (int jn = 0; jn < 4; ++jn) {
      const int col = n0 + wn + jn * 16 + lane16;
      const float bb = bias[col];
#pragma unroll
      for (int i = 0; i < 4; ++i) {
        const int rbase = m0 + wm + i * 16 + quad * 4;
#pragma unroll
        for (int r = 0; r < 4; ++r) {
          const float v = (acc[i][jn][r] + bb) * oscale;
          if (mode == 2) ((float*)Cv)[(long)(rbase + r) * D_MODEL + col] = v;
          else           ((u16*)Cv)[(long)(rbase + r) * D_MODEL + col] = f2bf(v);
        }
      }
    }
  }
}

// ---------------- Causal flash attention: LDS-staged K/V, 4 strips/block ----
// Block = 4 waves; wave w owns strip sw = 4g+w (32 q-rows), full accumulator.
// K/V chunk tiles staged in LDS once per block, consumed by all 4 waves;
// double-buffered, reg-staged, loads issued a full phase ahead (T14).
// T2 XOR-swizzle: K rows 128B, physical 16B-unit = logical ^ (row&7);
// V rows 64B, unit = logical ^ (row&3). Applied identically on the staging
// ds_write and the frag ds_read -> start banks uniform across the wave
// (round-3 padded layout had 8-way write conflicts: 5.37M counted).
// T5: setprio(1) around both MFMA clusters.
// Chunk count per block = 4(g+1) (even -> clean 2-chunk unroll, static reg
// buffers). Barriers block-uniform; compute guarded per-wave by c <= sw;
// causal mask only on the peeled diagonal (c == sw). Q pre-scaled by
// 1/sqrt(dk)*log2e (folded into Q GEMM) -> bare v_exp_f32.
// Grid: 1024 blocks; same-bh -> same XCD (id%8 round-robin), heavy-g first.
// Q,K: [B,S,D] bf16. VtX: chunk-interleaved [b*1024+chan][SEQ]. O: bf16.
__global__ __launch_bounds__(256, 3)
void attn_causal(const u16* __restrict__ Q, const u16* __restrict__ K,
                 const u16* __restrict__ VtX, u16* __restrict__ O)
{
  __shared__ __align__(16) u16 Kb[2][32][64];   // 8KB, swizzled (see above)
  __shared__ __align__(16) u16 Vb[2][64][32];   // 8KB, swizzled
  const int t = threadIdx.x;
  const int w = t >> 6, l = t & 63;
  const int quad = l >> 4, lane16 = l & 15;

  const int lin = blockIdx.x;        // 0..1023
  const int xcd = lin & 7;
  const int j = lin >> 3;            // 0..127
  const int bh = xcd * 8 + (j & 7);  // same bh -> same XCD (id%8 round-robin)
  const int g = 15 - (j >> 3);       // 0..15, heavy blocks first
  const int b = bh >> 4, h = bh & 15;
  const int sw = 4 * g + w;          // this wave's strip (32 q-rows)
  const int cmax = 4 * g + 3;        // last chunk any wave in block needs
  const int qbase = sw * 32;

  const long qkbase = (long)b * SEQ * D_MODEL + h * DK;

  // Q B-frags (x32): lane(q=lane16, quad) holds Q[q][ks*32+quad*8 ..+7]
  bf16x8 qf[2][2];
#pragma unroll
  for (int qi = 0; qi < 2; ++qi)
#pragma unroll
    for (int ks = 0; ks < 2; ++ks)
      qf[qi][ks] = *(const bf16x8*)&Q[qkbase +
          (long)(qbase + qi * 16 + lane16) * D_MODEL + ks * 32 + quad * 8];

  // staging addresses: K chunk = 32 rows x 128B slice; V chunk = 64 rows x 64B
  const int krow = t >> 3, kc = t & 7;          // 256 thr: 32 rows x 8 units
  const char* Kgt = (const char*)(K + qkbase) + (long)krow * (D_MODEL * 2) + kc * 16;
  u16* KbD0 = &Kb[0][krow][(kc ^ (krow & 7)) * 8];
  u16* KbD1 = &Kb[1][krow][(kc ^ (krow & 7)) * 8];
  const int vrow = t >> 2, vc = t & 3;          // 256 thr: 64 rows x 4 units
  const char* Vgt = (const char*)(VtX + ((long)b * 1024 + h * 64) * SEQ) +
                    (long)vrow * (SEQ * 2) + vc * 16;
  u16* VbD0 = &Vb[0][vrow][(vc ^ (vrow & 3)) * 8];
  u16* VbD1 = &Vb[1][vrow][(vc ^ (vrow & 3)) * 8];

  f32x4 oacc[4][2] = {};     // [d][qi], O^T tiles for this wave's strip
  float lsum[2] = {0.f, 0.f};

  auto body = [&](const u16 (*Kbuf)[64], const u16 (*Vbuf)[32], bool diag) {
    // K A-frags from LDS (swizzled): lane(key=lane16, quad)
    bf16x8 kf[2][2];
#pragma unroll
    for (int kt = 0; kt < 2; ++kt)
#pragma unroll
      for (int ks = 0; ks < 2; ++ks)
        kf[kt][ks] = *(const bf16x8*)
            &Kbuf[kt * 16 + lane16][(((ks * 4 + quad) ^ (lane16 & 7)) * 8)];
    // Vt A-frags from LDS (swizzled)
    i32x4 vfd[4];
#pragma unroll
    for (int d = 0; d < 4; ++d)
      vfd[d] = *(const i32x4*)
          &Vbuf[d * 16 + lane16][((quad ^ (lane16 & 3)) * 8)];

    // S^T = K·Q^T  (Q pre-scaled; result is log2-domain score)
    f32x4 st[2][2] = {};     // [kt][qi]
    __builtin_amdgcn_s_setprio(1);
#pragma unroll
    for (int kt = 0; kt < 2; ++kt)
#pragma unroll
      for (int qi = 0; qi < 2; ++qi)
#pragma unroll
        for (int ks = 0; ks < 2; ++ks)
          st[kt][qi] = __builtin_amdgcn_mfma_f32_16x16x32_bf16(kf[kt][ks], qf[qi][ks], st[kt][qi], 0, 0, 0);
    __builtin_amdgcn_s_setprio(0);

    // exp2 (raw v_exp_f32), causal mask only on the peeled diagonal chunk
    u32 pb[2][2][2];         // [kt][qi][pair]
#pragma unroll
    for (int kt = 0; kt < 2; ++kt)
#pragma unroll
      for (int qi = 0; qi < 2; ++qi) {
        float pv[4];
#pragma unroll
        for (int r = 0; r < 4; ++r) {
          float p = __builtin_amdgcn_exp2f(st[kt][qi][r]);
          if (diag && (kt * 16 + quad * 4 + r > qi * 16 + lane16)) p = 0.f;
          pv[r] = p;
        }
        lsum[qi] += (pv[0] + pv[1]) + (pv[2] + pv[3]);
        pb[kt][qi][0] = pack_bf2(pv[0], pv[1]);
        pb[kt][qi][1] = pack_bf2(pv[2], pv[3]);
      }

    // O^T += Vt·P^T  (x16; P^T B-frag = packed scores, layout identity)
    __builtin_amdgcn_s_setprio(1);
#pragma unroll
    for (int d = 0; d < 4; ++d) {
      const s16x4 va0 = cast_s16x4((u32)vfd[d].x, (u32)vfd[d].y);
      const s16x4 va1 = cast_s16x4((u32)vfd[d].z, (u32)vfd[d].w);
#pragma unroll
      for (int qi = 0; qi < 2; ++qi) {
        const s16x4 pb0 = cast_s16x4(pb[0][qi][0], pb[0][qi][1]);
        const s16x4 pb1 = cast_s16x4(pb[1][qi][0], pb[1][qi][1]);
        oacc[d][qi] = mfma16(va0, pb0, oacc[d][qi]);
        oacc[d][qi] = mfma16(va1, pb1, oacc[d][qi]);
      }
    }
    __builtin_amdgcn_s_setprio(0);
  };

  // ---- staged chunk loop (chunks 0..cmax, count = 4(g+1), even) ----
  // K chunk byte stride: 32 rows * 2048B = 65536; V chunk byte stride: 64.
  {
    // prologue: stage chunk 0, prefetch chunks 1,2 into regs
    i32x4 a0 = *(const i32x4*)(Kgt);
    i32x4 a1 = *(const i32x4*)(Vgt);
    *(i32x4*)KbD0 = a0;
    *(i32x4*)VbD0 = a1;
  }
  i32x4 gKA = *(const i32x4*)(Kgt + 65536);
  i32x4 gVA = *(const i32x4*)(Vgt + 64);
  i32x4 gKB = *(const i32x4*)(Kgt + 2 * 65536);
  i32x4 gVB = *(const i32x4*)(Vgt + 2 * 64);
  __syncthreads();

  for (int c = 0; c <= cmax; c += 2) {
    // state: buf0 = chunk c (ready); gA = c+1; gB = c+2 (if exists)
    *(i32x4*)KbD1 = gKA;
    *(i32x4*)VbD1 = gVA;
    if (c + 3 <= cmax) {
      gKA = *(const i32x4*)(Kgt + (long)(c + 3) * 65536);
      gVA = *(const i32x4*)(Vgt + (long)(c + 3) * 64);
    }
    if (c <= sw) body(Kb[0], Vb[0], c == sw);
    __syncthreads();                  // buf1 (chunk c+1) ready
    if (c + 2 <= cmax) {
      *(i32x4*)KbD0 = gKB;
      *(i32x4*)VbD0 = gVB;
      if (c + 4 <= cmax) {
        gKB = *(const i32x4*)(Kgt + (long)(c + 4) * 65536);
        gVB = *(const i32x4*)(Vgt + (long)(c + 4) * 64);
      }
    }
    if (c + 1 <= sw) body(Kb[1], Vb[1], (c + 1) == sw);
    __syncthreads();                  // buf0 (chunk c+2) ready
  }

  // ---- softmax denominator: reduce lsum across quads, then epilogue ----
  float linv[2];
#pragma unroll
  for (int qi = 0; qi < 2; ++qi) {
    float v = lsum[qi];
    v += __shfl_xor(v, 16);
    v += __shfl_xor(v, 32);
    linv[qi] = 1.f / v;
  }

  // epilogue: O[q][dk] = oacc^T / l ; lane writes 4 consecutive dk as b64
#pragma unroll
  for (int qi = 0; qi < 2; ++qi) {
    const long row = (long)b * SEQ + qbase + qi * 16 + lane16;
#pragma unroll
    for (int d = 0; d < 4; ++d) {
      const u32 p0 = ((u32)f2bf(oacc[d][qi][0] * linv[qi])) |
                     ((u32)f2bf(oacc[d][qi][1] * linv[qi]) << 16);
      const u32 p1 = ((u32)f2bf(oacc[d][qi][2] * linv[qi])) |
                     ((u32)f2bf(oacc[d][qi][3] * linv[qi]) << 16);
      u32x2 pk = {p0, p1};
      *(u32x2*)&O[row * D_MODEL + h * 64 + d * 16 + quad * 4] = pk;
    }
  }
}

extern "C" void kernel_launch(void* const* d_in, const int* in_sizes, int n_in,
                              void* d_out, int out_size, void* d_ws, size_t ws_size,
                              hipStream_t stream) {
  const float* q  = (const float*)d_in[0];
  const float* k  = (const float*)d_in[1];
  const float* v  = (const float*)d_in[2];
  // d_in[3]: causal mask (tril) — semantics hardcoded in attn_causal
  const float* Wq = (const float*)d_in[4];
  const float* bq = (const float*)d_in[5];
  const float* Wk = (const float*)d_in[6];
  const float* bk = (const float*)d_in[7];
  const float* Wv = (const float*)d_in[8];
  const float* bv = (const float*)d_in[9];
  const float* Wo = (const float*)d_in[10];
  const float* bo = (const float*)d_in[11];
  float* out = (float*)d_out;

  const size_t NT = (size_t)MTOT * D_MODEL;
  const size_t NW = (size_t)D_MODEL * D_MODEL;

  u16* w0  = (u16*)d_ws;
  u16* qb  = w0;
  u16* kb  = w0 + NT;
  u16* vb  = w0 + 2 * NT;
  u16* Wqb = w0 + 3 * NT;
  u16* Wkb = Wqb + NW;
  u16* Wvb = Wqb + 2 * NW;
  u16* Wob = Wqb + 3 * NW;
  u16* Qp  = (u16*)d_out;        // d_out doubles as bf16 scratch until final GEMM
  u16* Kp  = (u16*)d_out + NT;
  u16* Vpt = qb;                 // qb dead after GEMM1 (VtX layout)
  u16* Xp  = kb;                 // kb dead after GEMM2

  const dim3 blk(256);

  CvtArgs ca;
  ca.s[0] = q;  ca.d[0] = qb;  ca.n[0] = (int)NT;
  ca.s[1] = k;  ca.d[1] = kb;  ca.n[1] = (int)NT;
  ca.s[2] = v;  ca.d[2] = vb;  ca.n[2] = (int)NT;
  ca.s[3] = Wq; ca.d[3] = Wqb; ca.n[3] = (int)NW;
  ca.s[4] = Wk; ca.d[4] = Wkb; ca.n[4] = (int)NW;
  ca.s[5] = Wv; ca.d[5] = Wvb; ca.n[5] = (int)NW;
  ca.s[6] = Wo; ca.d[6] = Wob; ca.n[6] = (int)NW;
  cvt_multi<<<dim3(4096, 7), blk, 0, stream>>>(ca);

  const float SC = 0.125f * 1.4426950408889634f;   // 1/sqrt(dk) * log2(e)

  // QKV projections, one batched dispatch (z = 0,1,2; z=2 is the VT layout)
  GBatch g1;
  g1.A[0] = qb; g1.W[0] = Wqb; g1.bias[0] = bq; g1.C[0] = Qp;  g1.osc[0] = SC;  g1.mode[0] = 0;
  g1.A[1] = kb; g1.W[1] = Wkb; g1.bias[1] = bk; g1.C[1] = Kp;  g1.osc[1] = 1.f; g1.mode[1] = 0;
  g1.A[2] = vb; g1.W[2] = Wvb; g1.bias[2] = bv; g1.C[2] = Vpt; g1.osc[2] = 1.f; g1.mode[2] = 1;
  gemm_bt_bias<<<dim3(MTOT / 128, D_MODEL / 128, 3), blk, 0, stream>>>(g1);

  const dim3 agrid(1024);
  attn_causal<<<agrid, blk, 0, stream>>>(Qp, Kp, Vpt, Xp);

  // output projection (f32 out); only z=0 used
  GBatch g2;
  for (int i = 0; i < 3; ++i) {
    g2.A[i] = Xp; g2.W[i] = Wob; g2.bias[i] = bo; g2.C[i] = out;
    g2.osc[i] = 1.f; g2.mode[i] = 2;
  }
  gemm_bt_bias<<<dim3(MTOT / 128, D_MODEL / 128, 1), blk, 0, stream>>>(g2);
}

// Round 7
// 312.350 us; speedup vs baseline: 1.4272x; 1.0119x over previous
//
#include <hip/hip_runtime.h>
#include <hip/hip_bf16.h>
#include <stdint.h>

#define D_MODEL 1024
#define NUM_HEADS 16
#define DK 64
#define BATCH 4
#define SEQ 2048
#define MTOT (BATCH * SEQ)   // 8192 tokens

typedef unsigned short u16;
typedef unsigned int u32;
typedef __bf16 bf16x8 __attribute__((ext_vector_type(8)));
typedef float f32x4 __attribute__((ext_vector_type(4)));
typedef short s16x4 __attribute__((ext_vector_type(4)));
typedef int   i32x4 __attribute__((ext_vector_type(4)));
typedef int   i32x2 __attribute__((ext_vector_type(2)));
typedef uint  u32x2 __attribute__((ext_vector_type(2)));

// v_mfma_f32_16x16x16_bf16 (gfx90a+ "_1k" builtin name): A,B = 2 VGPRs (4 bf16), C/D = 4.
__device__ __forceinline__ f32x4 mfma16(s16x4 a, s16x4 b, f32x4 c) {
  return __builtin_amdgcn_mfma_f32_16x16x16bf16_1k(a, b, c, 0, 0, 0);
}

__device__ __forceinline__ u16 f2bf(float f) {
  union { float f; unsigned u; } c; c.f = f;
  unsigned u = c.u + 0x7fffu + ((c.u >> 16) & 1u);   // RNE
  return (u16)(u >> 16);
}
// pack two f32 into bf16x2 (truncate) — 1 instr
__device__ __forceinline__ u32 pack_bf2(float f0, float f1) {
  return __builtin_amdgcn_perm(__float_as_uint(f1), __float_as_uint(f0), 0x07060302u);
}
__device__ __forceinline__ s16x4 cast_s16x4(u32 lo, u32 hi) {
  u32x2 t = {lo, hi};
  return (s16x4)t;
}

// async global->LDS, 16B per lane (GEMM staging; LDS dst contiguous per wave).
__device__ __forceinline__ void async16(void* g, void* lds) {
  __builtin_amdgcn_global_load_lds(
      (__attribute__((address_space(1))) void*)g,
      (__attribute__((address_space(3))) void*)lds,
      16, 0, 0);
}

// ---------------- f32 -> bf16, all 7 tensors in one dispatch ----------------
struct CvtArgs {
  const float* s[7];
  u16* d[7];
  int n[7];
};
__global__ __launch_bounds__(256)
void cvt_multi(CvtArgs a) {
  const int which = blockIdx.y;
  const int n = a.n[which];
  const int i = (blockIdx.x * 256 + threadIdx.x) * 8;
  if (i >= n) return;
  const float* s = a.s[which];
  u16* d = a.d[which];
  const float4 x = *(const float4*)(s + i);
  const float4 y = *(const float4*)(s + i + 4);
  *(ushort4*)(d + i)     = make_ushort4(f2bf(x.x), f2bf(x.y), f2bf(x.z), f2bf(x.w));
  *(ushort4*)(d + i + 4) = make_ushort4(f2bf(y.x), f2bf(y.y), f2bf(y.z), f2bf(y.w));
}

// ---------------- GEMM: C = (A @ W^T + bias) * oscale -----------------------
// 128x128 tile, BK=32, 3-BUFFER LDS pipeline with COUNTED vmcnt (T4):
// iteration c stages chunk c+2, computes chunk c, then waits vmcnt(4) —
// i.e. only until chunk c+1's 4 loads landed, leaving c+2's in flight across
// the barrier. Round-6 drained vmcnt(0) per step (the just-issued loads!),
// exposing ~500cy/step: MfmaUtil 21%, VALU 14%, HBM 17% — all idle.
// Raw s_barrier + sched_barrier(0) (rule #18: pin LDS reads behind barrier).
// LDS: 3 x 16KB chunks = 48KB; VT restage T (33KB) unions over [0..16895]
// (only after the post-loop __syncthreads).
// Batched: grid.z picks per-tensor pointers (QKV in one dispatch).
// mode 0: C bf16 [M,1024].  mode 2: C f32 [M,1024].
// mode 1 (VT): C -> VtX[b*1024+chan][SEQ] bf16, key dim chunk-interleaved:
//   within each 32-key chunk, key kt*16+qd*4+j stored at pos qd*8+kt*4+j.
struct GBatch {
  const u16* A[3]; const u16* W[3]; const float* bias[3];
  void* C[3]; float osc[3]; int mode[3];
};
__global__ __launch_bounds__(256, 2)
void gemm_bt_bias(GBatch ga)
{
  __shared__ __align__(16) u16 smem[24576];   // 3 x (As 4096 + Bs 4096) u16
  const int z = blockIdx.z;
  const u16* __restrict__ A = ga.A[z];
  const u16* __restrict__ W = ga.W[z];
  const float* __restrict__ bias = ga.bias[z];
  void* __restrict__ Cv = ga.C[z];
  const float oscale = ga.osc[z];
  const int mode = ga.mode[z];

  const int t = threadIdx.x;
  const int w = t >> 6, l = t & 63;
  const int quad = l >> 4, lane16 = l & 15;
  const int m0 = blockIdx.x * 128;
  const int n0 = blockIdx.y * 128;
  const int wm = (w >> 1) * 64, wn = (w & 1) * 64;

  const int srow = t >> 2;
  const int scol = (t & 3) * 8;
  const u16* Ag = A + (long)(m0 + srow) * D_MODEL + scol;
  const u16* Wg = W + (long)(n0 + srow) * D_MODEL + scol;

  f32x4 acc[4][4] = {};

  auto stage = [&](int buf, int k0) {
    u16* As_ = smem + buf * 8192;
    u16* Bs_ = As_ + 4096;
    async16((void*)(Ag + k0), As_ + w * 512);
    async16((void*)(Ag + 64 * D_MODEL + k0), As_ + w * 512 + 2048);
    async16((void*)(Wg + k0), Bs_ + w * 512);
    async16((void*)(Wg + 64 * D_MODEL + k0), Bs_ + w * 512 + 2048);
  };
  auto compute = [&](int buf) {
    const u16* As_ = smem + buf * 8192;
    const u16* Bs_ = As_ + 4096;
    bf16x8 af[4], bfr[4];
#pragma unroll
    for (int i = 0; i < 4; ++i)
      af[i] = *(const bf16x8*)&As_[(wm + i * 16 + lane16) * 32 + quad * 8];
#pragma unroll
    for (int i = 0; i < 4; ++i)
      bfr[i] = *(const bf16x8*)&Bs_[(wn + i * 16 + lane16) * 32 + quad * 8];
#pragma unroll
    for (int i = 0; i < 4; ++i)
#pragma unroll
      for (int jn = 0; jn < 4; ++jn)
        acc[i][jn] = __builtin_amdgcn_mfma_f32_16x16x32_bf16(af[i], bfr[jn], acc[i][jn], 0, 0, 0);
  };

  // prologue: chunks 0,1 in flight; wait chunk 0 (leave chunk 1's 4 loads)
  stage(0, 0);
  stage(1, 32);
  asm volatile("s_waitcnt vmcnt(4)" ::: "memory");
  __builtin_amdgcn_s_barrier();
  __builtin_amdgcn_sched_barrier(0);

  int buf = 0;
#pragma unroll 1
  for (int c = 0; c < 32; ++c) {
    if (c + 2 < 32) stage((buf + 2 >= 3) ? buf - 1 : buf + 2, (c + 2) * 32);
    compute(buf);
    if (c < 30) {
      asm volatile("s_waitcnt vmcnt(4)" ::: "memory");   // chunk c+1 landed
      __builtin_amdgcn_s_barrier();
      __builtin_amdgcn_sched_barrier(0);
    } else if (c == 30) {
      asm volatile("s_waitcnt vmcnt(0)" ::: "memory");   // tail: chunk 31
      __builtin_amdgcn_s_barrier();
      __builtin_amdgcn_sched_barrier(0);
    }
    buf = (buf + 1 == 3) ? 0 : buf + 1;
  }
  __syncthreads();   // all waves done reading smem before T union / exit

  if (mode == 1) {
    // restage through LDS (reuses smem — main loop done): T[dk][key], pad 132
    u16* T = smem;
#pragma unroll
    for (int jn = 0; jn < 4; ++jn) {
      const int col = wn + jn * 16 + lane16;          // dk_local
      const float bb = bias[n0 + col];
#pragma unroll
      for (int i = 0; i < 4; ++i) {
        const int rbase = wm + i * 16 + quad * 4;     // key_local
#pragma unroll
        for (int r = 0; r < 4; ++r)
          T[col * 132 + rbase + r] = f2bf((acc[i][jn][r] + bb) * oscale);
      }
    }
    __syncthreads();
    // coalesced, chunk-interleaved writeout: out pos 4a..4a+3 <- keys
    // (a>>3)*32 + ((a&7)>>1)*4 + (a&1)*16 + {0..3}
    const int bq = m0 >> 11, sbase = m0 & 2047;
    const int a = t & 31;
    const int keystart = ((a >> 3) * 32) + (((a & 7) >> 1) * 4) + ((a & 1) * 16);
    u16* orow = (u16*)Cv + ((long)bq * 1024 + n0) * SEQ + sbase + 4 * a;
#pragma unroll
    for (int pass = 0; pass < 16; ++pass) {
      const int dkl = (t >> 5) + 8 * pass;
      *(u32x2*)(orow + (long)dkl * SEQ) = *(const u32x2*)&T[dkl * 132 + keystart];
    }
  } else {
#pragma unroll
    for (int jn = 0; jn < 4; ++jn) {
      const int col = n0 + wn + jn * 16 + lane16;
      const float bb = bias[col];
#pragma unroll
      for (int i = 0; i < 4; ++i) {
        const int rbase = m0 + wm + i * 16 + quad * 4;
#pragma unroll
        for (int r = 0; r < 4; ++r) {
          const float v = (acc[i][jn][r] + bb) * oscale;
          if (mode == 2) ((float*)Cv)[(long)(rbase + r) * D_MODEL + col] = v;
          else           ((u16*)Cv)[(long)(rbase + r) * D_MODEL + col] = f2bf(v);
        }
      }
    }
  }
}

// ---------------- Causal flash attention: LDS-staged K/V, 4 strips/block ----
// (unchanged from round 6 — passed; GEMM is the measured bottleneck)
__global__ __launch_bounds__(256, 3)
void attn_causal(const u16* __restrict__ Q, const u16* __restrict__ K,
                 const u16* __restrict__ VtX, u16* __restrict__ O)
{
  __shared__ __align__(16) u16 Kb[2][32][64];   // 8KB, swizzled
  __shared__ __align__(16) u16 Vb[2][64][32];   // 8KB, swizzled
  const int t = threadIdx.x;
  const int w = t >> 6, l = t & 63;
  const int quad = l >> 4, lane16 = l & 15;

  const int lin = blockIdx.x;        // 0..1023
  const int xcd = lin & 7;
  const int j = lin >> 3;            // 0..127
  const int bh = xcd * 8 + (j & 7);  // same bh -> same XCD (id%8 round-robin)
  const int g = 15 - (j >> 3);       // 0..15, heavy blocks first
  const int b = bh >> 4, h = bh & 15;
  const int sw = 4 * g + w;          // this wave's strip (32 q-rows)
  const int cmax = 4 * g + 3;        // last chunk any wave in block needs
  const int qbase = sw * 32;

  const long qkbase = (long)b * SEQ * D_MODEL + h * DK;

  // Q B-frags (x32): lane(q=lane16, quad) holds Q[q][ks*32+quad*8 ..+7]
  bf16x8 qf[2][2];
#pragma unroll
  for (int qi = 0; qi < 2; ++qi)
#pragma unroll
    for (int ks = 0; ks < 2; ++ks)
      qf[qi][ks] = *(const bf16x8*)&Q[qkbase +
          (long)(qbase + qi * 16 + lane16) * D_MODEL + ks * 32 + quad * 8];

  // staging addresses: K chunk = 32 rows x 128B slice; V chunk = 64 rows x 64B
  const int krow = t >> 3, kc = t & 7;          // 256 thr: 32 rows x 8 units
  const char* Kgt = (const char*)(K + qkbase) + (long)krow * (D_MODEL * 2) + kc * 16;
  u16* KbD0 = &Kb[0][krow][(kc ^ (krow & 7)) * 8];
  u16* KbD1 = &Kb[1][krow][(kc ^ (krow & 7)) * 8];
  const int vrow = t >> 2, vc = t & 3;          // 256 thr: 64 rows x 4 units
  const char* Vgt = (const char*)(VtX + ((long)b * 1024 + h * 64) * SEQ) +
                    (long)vrow * (SEQ * 2) + vc * 16;
  u16* VbD0 = &Vb[0][vrow][(vc ^ (vrow & 3)) * 8];
  u16* VbD1 = &Vb[1][vrow][(vc ^ (vrow & 3)) * 8];

  f32x4 oacc[4][2] = {};     // [d][qi], O^T tiles for this wave's strip
  float lsum[2] = {0.f, 0.f};

  auto body = [&](const u16 (*Kbuf)[64], const u16 (*Vbuf)[32], bool diag) {
    // K A-frags from LDS (swizzled): lane(key=lane16, quad)
    bf16x8 kf[2][2];
#pragma unroll
    for (int kt = 0; kt < 2; ++kt)
#pragma unroll
      for (int ks = 0; ks < 2; ++ks)
        kf[kt][ks] = *(const bf16x8*)
            &Kbuf[kt * 16 + lane16][(((ks * 4 + quad) ^ (lane16 & 7)) * 8)];
    // Vt A-frags from LDS (swizzled)
    i32x4 vfd[4];
#pragma unroll
    for (int d = 0; d < 4; ++d)
      vfd[d] = *(const i32x4*)
          &Vbuf[d * 16 + lane16][((quad ^ (lane16 & 3)) * 8)];

    // S^T = K·Q^T  (Q pre-scaled; result is log2-domain score)
    f32x4 st[2][2] = {};     // [kt][qi]
    __builtin_amdgcn_s_setprio(1);
#pragma unroll
    for (int kt = 0; kt < 2; ++kt)
#pragma unroll
      for (int qi = 0; qi < 2; ++qi)
#pragma unroll
        for (int ks = 0; ks < 2; ++ks)
          st[kt][qi] = __builtin_amdgcn_mfma_f32_16x16x32_bf16(kf[kt][ks], qf[qi][ks], st[kt][qi], 0, 0, 0);
    __builtin_amdgcn_s_setprio(0);

    // exp2 (raw v_exp_f32), causal mask only on the peeled diagonal chunk
    u32 pb[2][2][2];         // [kt][qi][pair]
#pragma unroll
    for (int kt = 0; kt < 2; ++kt)
#pragma unroll
      for (int qi = 0; qi < 2; ++qi) {
        float pv[4];
#pragma unroll
        for (int r = 0; r < 4; ++r) {
          float p = __builtin_amdgcn_exp2f(st[kt][qi][r]);
          if (diag && (kt * 16 + quad * 4 + r > qi * 16 + lane16)) p = 0.f;
          pv[r] = p;
        }
        lsum[qi] += (pv[0] + pv[1]) + (pv[2] + pv[3]);
        pb[kt][qi][0] = pack_bf2(pv[0], pv[1]);
        pb[kt][qi][1] = pack_bf2(pv[2], pv[3]);
      }

    // O^T += Vt·P^T  (x16; P^T B-frag = packed scores, layout identity)
    __builtin_amdgcn_s_setprio(1);
#pragma unroll
    for (int d = 0; d < 4; ++d) {
      const s16x4 va0 = cast_s16x4((u32)vfd[d].x, (u32)vfd[d].y);
      const s16x4 va1 = cast_s16x4((u32)vfd[d].z, (u32)vfd[d].w);
#pragma unroll
      for (int qi = 0; qi < 2; ++qi) {
        const s16x4 pb0 = cast_s16x4(pb[0][qi][0], pb[0][qi][1]);
        const s16x4 pb1 = cast_s16x4(pb[1][qi][0], pb[1][qi][1]);
        oacc[d][qi] = mfma16(va0, pb0, oacc[d][qi]);
        oacc[d][qi] = mfma16(va1, pb1, oacc[d][qi]);
      }
    }
    __builtin_amdgcn_s_setprio(0);
  };

  // ---- staged chunk loop (chunks 0..cmax, count = 4(g+1), even) ----
  // K chunk byte stride: 32 rows * 2048B = 65536; V chunk byte stride: 64.
  {
    // prologue: stage chunk 0, prefetch chunks 1,2 into regs
    i32x4 a0 = *(const i32x4*)(Kgt);
    i32x4 a1 = *(const i32x4*)(Vgt);
    *(i32x4*)KbD0 = a0;
    *(i32x4*)VbD0 = a1;
  }
  i32x4 gKA = *(const i32x4*)(Kgt + 65536);
  i32x4 gVA = *(const i32x4*)(Vgt + 64);
  i32x4 gKB = *(const i32x4*)(Kgt + 2 * 65536);
  i32x4 gVB = *(const i32x4*)(Vgt + 2 * 64);
  __syncthreads();

  for (int c = 0; c <= cmax; c += 2) {
    // state: buf0 = chunk c (ready); gA = c+1; gB = c+2 (if exists)
    *(i32x4*)KbD1 = gKA;
    *(i32x4*)VbD1 = gVA;
    if (c + 3 <= cmax) {
      gKA = *(const i32x4*)(Kgt + (long)(c + 3) * 65536);
      gVA = *(const i32x4*)(Vgt + (long)(c + 3) * 64);
    }
    if (c <= sw) body(Kb[0], Vb[0], c == sw);
    __syncthreads();                  // buf1 (chunk c+1) ready
    if (c + 2 <= cmax) {
      *(i32x4*)KbD0 = gKB;
      *(i32x4*)VbD0 = gVB;
      if (c + 4 <= cmax) {
        gKB = *(const i32x4*)(Kgt + (long)(c + 4) * 65536);
        gVB = *(const i32x4*)(Vgt + (long)(c + 4) * 64);
      }
    }
    if (c + 1 <= sw) body(Kb[1], Vb[1], (c + 1) == sw);
    __syncthreads();                  // buf0 (chunk c+2) ready
  }

  // ---- softmax denominator: reduce lsum across quads, then epilogue ----
  float linv[2];
#pragma unroll
  for (int qi = 0; qi < 2; ++qi) {
    float v = lsum[qi];
    v += __shfl_xor(v, 16);
    v += __shfl_xor(v, 32);
    linv[qi] = 1.f / v;
  }

  // epilogue: O[q][dk] = oacc^T / l ; lane writes 4 consecutive dk as b64
#pragma unroll
  for (int qi = 0; qi < 2; ++qi) {
    const long row = (long)b * SEQ + qbase + qi * 16 + lane16;
#pragma unroll
    for (int d = 0; d < 4; ++d) {
      const u32 p0 = ((u32)f2bf(oacc[d][qi][0] * linv[qi])) |
                     ((u32)f2bf(oacc[d][qi][1] * linv[qi]) << 16);
      const u32 p1 = ((u32)f2bf(oacc[d][qi][2] * linv[qi])) |
                     ((u32)f2bf(oacc[d][qi][3] * linv[qi]) << 16);
      u32x2 pk = {p0, p1};
      *(u32x2*)&O[row * D_MODEL + h * 64 + d * 16 + quad * 4] = pk;
    }
  }
}

extern "C" void kernel_launch(void* const* d_in, const int* in_sizes, int n_in,
                              void* d_out, int out_size, void* d_ws, size_t ws_size,
                              hipStream_t stream) {
  const float* q  = (const float*)d_in[0];
  const float* k  = (const float*)d_in[1];
  const float* v  = (const float*)d_in[2];
  // d_in[3]: causal mask (tril) — semantics hardcoded in attn_causal
  const float* Wq = (const float*)d_in[4];
  const float* bq = (const float*)d_in[5];
  const float* Wk = (const float*)d_in[6];
  const float* bk = (const float*)d_in[7];
  const float* Wv = (const float*)d_in[8];
  const float* bv = (const float*)d_in[9];
  const float* Wo = (const float*)d_in[10];
  const float* bo = (const float*)d_in[11];
  float* out = (float*)d_out;

  const size_t NT = (size_t)MTOT * D_MODEL;
  const size_t NW = (size_t)D_MODEL * D_MODEL;

  u16* w0  = (u16*)d_ws;
  u16* qb  = w0;
  u16* kb  = w0 + NT;
  u16* vb  = w0 + 2 * NT;
  u16* Wqb = w0 + 3 * NT;
  u16* Wkb = Wqb + NW;
  u16* Wvb = Wqb + 2 * NW;
  u16* Wob = Wqb + 3 * NW;
  u16* Qp  = (u16*)d_out;        // d_out doubles as bf16 scratch until final GEMM
  u16* Kp  = (u16*)d_out + NT;
  u16* Vpt = qb;                 // qb dead after GEMM1 (VtX layout)
  u16* Xp  = kb;                 // kb dead after GEMM2

  const dim3 blk(256);

  CvtArgs ca;
  ca.s[0] = q;  ca.d[0] = qb;  ca.n[0] = (int)NT;
  ca.s[1] = k;  ca.d[1] = kb;  ca.n[1] = (int)NT;
  ca.s[2] = v;  ca.d[2] = vb;  ca.n[2] = (int)NT;
  ca.s[3] = Wq; ca.d[3] = Wqb; ca.n[3] = (int)NW;
  ca.s[4] = Wk; ca.d[4] = Wkb; ca.n[4] = (int)NW;
  ca.s[5] = Wv; ca.d[5] = Wvb; ca.n[5] = (int)NW;
  ca.s[6] = Wo; ca.d[6] = Wob; ca.n[6] = (int)NW;
  cvt_multi<<<dim3(4096, 7), blk, 0, stream>>>(ca);

  const float SC = 0.125f * 1.4426950408889634f;   // 1/sqrt(dk) * log2(e)

  // QKV projections, one batched dispatch (z = 0,1,2; z=2 is the VT layout)
  GBatch g1;
  g1.A[0] = qb; g1.W[0] = Wqb; g1.bias[0] = bq; g1.C[0] = Qp;  g1.osc[0] = SC;  g1.mode[0] = 0;
  g1.A[1] = kb; g1.W[1] = Wkb; g1.bias[1] = bk; g1.C[1] = Kp;  g1.osc[1] = 1.f; g1.mode[1] = 0;
  g1.A[2] = vb; g1.W[2] = Wvb; g1.bias[2] = bv; g1.C[2] = Vpt; g1.osc[2] = 1.f; g1.mode[2] = 1;
  gemm_bt_bias<<<dim3(MTOT / 128, D_MODEL / 128, 3), blk, 0, stream>>>(g1);

  const dim3 agrid(1024);
  attn_causal<<<agrid, blk, 0, stream>>>(Qp, Kp, Vpt, Xp);

  // output projection (f32 out); only z=0 used
  GBatch g2;
  for (int i = 0; i < 3; ++i) {
    g2.A[i] = Xp; g2.W[i] = Wob; g2.bias[i] = bo; g2.C[i] = out;
    g2.osc[i] = 1.f; g2.mode[i] = 2;
  }
  gemm_bt_bias<<<dim3(MTOT / 128, D_MODEL / 128, 1), blk, 0, stream>>>(g2);
}